// Round 6
// baseline (10019.781 us; speedup 1.0000x reference)
//
#include <hip/hip_runtime.h>
#include <hip/hip_bf16.h>
#include <math.h>

#define BB 1024
#define TT 64
#define OBSN 64
#define ACTN 8
#define STOCHN 32
#define DETERN 512
#define HIDN 512
#define G3N 1536
#define CATPI 40
#define OUTC 672
#define LNEPS 1e-3f
#define MINSTD 0.1f
#define UPDBIAS -1.0f
#define GROWS 16
#define KWBLK 64

typedef __attribute__((ext_vector_type(8))) short short8;
typedef __attribute__((ext_vector_type(4))) float f32x4;

__device__ __forceinline__ float sigmoidf_(float x) { return 1.f / (1.f + expf(-x)); }
__device__ __forceinline__ float siluf_(float x) { return x / (1.f + expf(-x)); }
__device__ __forceinline__ float softplusf_(float x) { return (x > 20.f) ? x : log1pf(expf(x)); }

__device__ __forceinline__ short f2b(float f) {
    __hip_bfloat16 h = __float2bfloat16(f);
    return __builtin_bit_cast(short, h);
}

__device__ __forceinline__ f32x4 mfma16(short8 a, short8 b, f32x4 c) {
    return __builtin_amdgcn_mfma_f32_16x16x32_bf16(a, b, c, 0, 0, 0);
}

// ---- swizzled bf16 [16][512] LDS tile: row stride 1024 B, 16B slots XOR'd by row&7 ----
__device__ __forceinline__ int swz(int row, int col) {
    return row * 1024 + ((((col >> 3) ^ (row & 7)) << 4) | ((col & 7) << 1));
}
__device__ __forceinline__ short8 frag_ld(const short* base, int row, int ks, int lk) {
    int slot = (ks * 4 + lk) ^ (row & 7);
    return *(const short8*)((const char*)base + row * 1024 + (slot << 4));
}
// ---- swizzled bf16 [16][64]: row stride 128 B, 8 slots ----
__device__ __forceinline__ int swz64(int row, int col) {
    return row * 128 + (((((col >> 3) ^ (row & 7)) & 7) << 4) | ((col & 7) << 1));
}
__device__ __forceinline__ short8 frag_ld64(const short* base, int row, int ks, int lk) {
    int slot = ((ks * 4 + lk) ^ (row & 7)) & 7;
    return *(const short8*)((const char*)base + row * 128 + (slot << 4));
}

// ---- cross-wave LN: caller supplies per-lane partial s/q for rows lk*4+i; returns m, iv ----
__device__ __forceinline__ void ln_combine(float s[4], float q[4], float invn, float* red, float* redc, int wid,
                                           int lr, int lk, float m[4], float iv[4]) {
#pragma unroll
    for (int msk = 1; msk <= 8; msk <<= 1)
#pragma unroll
        for (int i = 0; i < 4; ++i) {
            s[i] += __shfl_xor(s[i], msk);
            q[i] += __shfl_xor(q[i], msk);
        }
    if (lr == 0)
#pragma unroll
        for (int i = 0; i < 4; ++i) {
            red[(wid * 16 + lk * 4 + i) * 2 + 0] = s[i];
            red[(wid * 16 + lk * 4 + i) * 2 + 1] = q[i];
        }
    __syncthreads();
    int tid = threadIdx.x;
    if (tid < 32) {
        int row = tid >> 1, v = tid & 1;
        float a = 0.f;
#pragma unroll
        for (int w = 0; w < 8; ++w) a += red[(w * 16 + row) * 2 + v];
        redc[row * 2 + v] = a;
    }
    __syncthreads();
#pragma unroll
    for (int i = 0; i < 4; ++i) {
        int row = lk * 4 + i;
        float mm = redc[row * 2] * invn;
        float vv = redc[row * 2 + 1] * invn - mm * mm;
        m[i] = mm;
        iv[i] = rsqrtf(vv + LNEPS);
    }
}

// ---- dense 16xK @ Wt[N=512][K]^T -> LN -> silu -> bf16 swizzled dst ----
template <bool OBS_TAIL>
__device__ __forceinline__ void dense512(const short* A_lds, const __hip_bfloat16* Wt, int ldw,
                                         const __hip_bfloat16* op, const float* gg, const float* bb, short* dst,
                                         float* red, float* redc, int wid, int lr, int lk) {
    f32x4 acc[4] = {};
    const int c0 = wid * 64 + lr;
#pragma unroll 2
    for (int ks = 0; ks < 16; ++ks) {
        short8 a = frag_ld(A_lds, lr, ks, lk);
#pragma unroll
        for (int f = 0; f < 4; ++f) {
            short8 b = *(const short8*)(Wt + (size_t)(c0 + f * 16) * ldw + ks * 32 + lk * 8);
            acc[f] = mfma16(a, b, acc[f]);
        }
    }
    if constexpr (OBS_TAIL) {
#pragma unroll
        for (int ks = 0; ks < 2; ++ks) {
            short8 a = *(const short8*)(op + ks * 32 + lk * 8);
#pragma unroll
            for (int f = 0; f < 4; ++f) {
                short8 b = *(const short8*)(Wt + (size_t)(c0 + f * 16) * ldw + 512 + ks * 32 + lk * 8);
                acc[f] = mfma16(a, b, acc[f]);
            }
        }
    }
    float s[4] = {}, q[4] = {};
#pragma unroll
    for (int f = 0; f < 4; ++f)
#pragma unroll
        for (int i = 0; i < 4; ++i) {
            float v = acc[f][i];
            s[i] += v;
            q[i] += v * v;
        }
    float m[4], iv[4];
    ln_combine(s, q, 1.f / 512.f, red, redc, wid, lr, lk, m, iv);
#pragma unroll
    for (int f = 0; f < 4; ++f) {
        int col = c0 + f * 16;
        float g = gg[col], b = bb[col];
#pragma unroll
        for (int i = 0; i < 4; ++i) {
            float v = siluf_((acc[f][i] - m[i]) * iv[i] * g + b);
            *(short*)((char*)dst + swz(lk * 4 + i, col)) = f2b(v);
        }
    }
}

// ---- prior_in: x = silu(LN(a[16x64] @ WpiT[512][64]^T)) -> x_lds ----
__device__ __forceinline__ void prior_gemm(const short* a_lds, const __hip_bfloat16* WpiT, const float* g_pi,
                                           const float* b_pi, short* x_lds, float* red, float* redc, int wid,
                                           int lr, int lk) {
    f32x4 acc[4] = {};
    const int c0 = wid * 64 + lr;
#pragma unroll
    for (int ks = 0; ks < 2; ++ks) {
        short8 a = frag_ld64(a_lds, lr, ks, lk);
#pragma unroll
        for (int f = 0; f < 4; ++f) {
            short8 b = *(const short8*)(WpiT + (size_t)(c0 + f * 16) * 64 + ks * 32 + lk * 8);
            acc[f] = mfma16(a, b, acc[f]);
        }
    }
    float s[4] = {}, q[4] = {};
#pragma unroll
    for (int f = 0; f < 4; ++f)
#pragma unroll
        for (int i = 0; i < 4; ++i) {
            float v = acc[f][i];
            s[i] += v;
            q[i] += v * v;
        }
    float m[4], iv[4];
    ln_combine(s, q, 1.f / 512.f, red, redc, wid, lr, lk, m, iv);
#pragma unroll
    for (int f = 0; f < 4; ++f) {
        int col = c0 + f * 16;
        float g = g_pi[col], b = b_pi[col];
#pragma unroll
        for (int i = 0; i < 4; ++i) {
            float v = siluf_((acc[f][i] - m[i]) * iv[i] * g + b);
            *(short*)((char*)x_lds + swz(lk * 4 + i, col)) = f2b(v);
        }
    }
}

// ==== row-stationary persistent kernel: block owns 16 batch rows for all 64 steps ====
__global__ __launch_bounds__(512) void k_world(
    const int* __restrict__ isf, const float* __restrict__ action, const __hip_bfloat16* __restrict__ obsbf,
    const __hip_bfloat16* __restrict__ WpiT, const float* __restrict__ g_pi, const float* __restrict__ b_pi,
    const __hip_bfloat16* __restrict__ WgT, const float* __restrict__ g_gru, const float* __restrict__ b_gru,
    const __hip_bfloat16* __restrict__ WpoT, const float* __restrict__ g_po, const float* __restrict__ b_po,
    const __hip_bfloat16* __restrict__ WpnT, const float* __restrict__ g_pn, const float* __restrict__ b_pn,
    const __hip_bfloat16* __restrict__ WpsT, const float* __restrict__ b_ps,
    const __hip_bfloat16* __restrict__ WptT, const float* __restrict__ b_pt, const float* __restrict__ dinit,
    const float* __restrict__ sinit, float* __restrict__ out) {
    __shared__ short x_lds[16 * 512];
    __shared__ short dbf_lds[16 * 512];
    __shared__ short stage[16 * 512];
    __shared__ float statsf[2 * 16 * 64];
    __shared__ short a_lds[16 * 64];
    __shared__ float red[8 * 16 * 2];
    __shared__ float redc[16 * 2];
    __shared__ int flags[16];

    const int tid = threadIdx.x, wid = tid >> 6, lane = tid & 63, lr = lane & 15, lk = lane >> 4;
    const int grow = blockIdx.x * GROWS;
    const int c0 = wid * 64 + lr;
    float det[4][4];

    // ---- t=0 state: deter = dinit (always), stoch = sinit (always), action masked by is_first ----
#pragma unroll
    for (int f = 0; f < 4; ++f) {
        float dv = dinit[c0 + f * 16];
#pragma unroll
        for (int i = 0; i < 4; ++i) {
            det[f][i] = dv;
            *(short*)((char*)dbf_lds + swz(lk * 4 + i, c0 + f * 16)) = f2b(dv);
        }
    }
    {
        int row = tid >> 5, c = tid & 31;
        int f0 = isf[(size_t)(grow + row) * TT] > 0;
        *(short*)((char*)a_lds + swz64(row, c)) = f2b(sinit[c]);
        float av = (c < ACTN) ? (f0 ? 0.f : action[(size_t)(grow + row) * TT * ACTN + c]) : 0.f;
        *(short*)((char*)a_lds + swz64(row, 32 + c)) = f2b(av);
    }
    __syncthreads();
    prior_gemm(a_lds, WpiT, g_pi, b_pi, x_lds, red, redc, wid, lr, lk);
    __syncthreads();

    for (int t = 0; t < TT; ++t) {
        // ---- P1: GRU GEMM (K=1024: x then dbf), r/c/u-aligned N-partition + fused P2 update ----
        {
            f32x4 ar[4] = {}, acm[4] = {}, au[4] = {};
#pragma unroll 2
            for (int ks = 0; ks < 16; ++ks) {
                short8 a = frag_ld(x_lds, lr, ks, lk);
#pragma unroll
                for (int f = 0; f < 4; ++f) {
                    size_t rb = (size_t)(c0 + f * 16) * 1024 + ks * 32 + lk * 8;
                    short8 br = *(const short8*)(WgT + rb);
                    short8 bc = *(const short8*)(WgT + rb + (size_t)512 * 1024);
                    short8 bu = *(const short8*)(WgT + rb + (size_t)1024 * 1024);
                    ar[f] = mfma16(a, br, ar[f]);
                    acm[f] = mfma16(a, bc, acm[f]);
                    au[f] = mfma16(a, bu, au[f]);
                }
            }
#pragma unroll 2
            for (int ks = 0; ks < 16; ++ks) {
                short8 a = frag_ld(dbf_lds, lr, ks, lk);
#pragma unroll
                for (int f = 0; f < 4; ++f) {
                    size_t rb = (size_t)(c0 + f * 16) * 1024 + 512 + ks * 32 + lk * 8;
                    short8 br = *(const short8*)(WgT + rb);
                    short8 bc = *(const short8*)(WgT + rb + (size_t)512 * 1024);
                    short8 bu = *(const short8*)(WgT + rb + (size_t)1024 * 1024);
                    ar[f] = mfma16(a, br, ar[f]);
                    acm[f] = mfma16(a, bc, acm[f]);
                    au[f] = mfma16(a, bu, au[f]);
                }
            }
            float s[4] = {}, q[4] = {};
#pragma unroll
            for (int f = 0; f < 4; ++f)
#pragma unroll
                for (int i = 0; i < 4; ++i) {
                    float v0 = ar[f][i], v1 = acm[f][i], v2 = au[f][i];
                    s[i] += v0 + v1 + v2;
                    q[i] += v0 * v0 + v1 * v1 + v2 * v2;
                }
            float m[4], iv[4];
            ln_combine(s, q, 1.f / 1536.f, red, redc, wid, lr, lk, m, iv);
#pragma unroll
            for (int f = 0; f < 4; ++f) {
                int col = c0 + f * 16;
                float g_r = g_gru[col], b_r = b_gru[col];
                float g_c = g_gru[512 + col], b_c = b_gru[512 + col];
                float g_u = g_gru[1024 + col], b_u = b_gru[1024 + col];
#pragma unroll
                for (int i = 0; i < 4; ++i) {
                    int row = lk * 4 + i;
                    float rv = sigmoidf_((ar[f][i] - m[i]) * iv[i] * g_r + b_r);
                    float cv = (acm[f][i] - m[i]) * iv[i] * g_c + b_c;
                    float uv = sigmoidf_((au[f][i] - m[i]) * iv[i] * g_u + b_u + UPDBIAS);
                    float dn = uv * siluf_(rv * cv) + (1.f - uv) * det[f][i];
                    det[f][i] = dn;
                    out[((size_t)(grow + row) * TT + t) * OUTC + 160 + col] = dn;
                    *(short*)((char*)dbf_lds + swz(row, col)) = f2b(dn);
                }
            }
        }
        __syncthreads();
        // ---- P3a: hq = silu(LN(cat(deter,obs) @ W_pn)) -> stage ----
        {
            const __hip_bfloat16* op = obsbf + ((size_t)(grow + lr) * TT + t) * OBSN;
            dense512<true>(dbf_lds, WpnT, 576, op, g_pn, b_pn, stage, red, redc, wid, lr, lk);
        }
        __syncthreads();
        // qs = hq @ W_pt + b_pt  (waves 0-3)
        if (wid < 4) {
            f32x4 aq = {};
            int col = wid * 16 + lr;
#pragma unroll 2
            for (int ks = 0; ks < 16; ++ks) {
                short8 a = frag_ld(stage, lr, ks, lk);
                short8 b = *(const short8*)(WptT + (size_t)col * 512 + ks * 32 + lk * 8);
                aq = mfma16(a, b, aq);
            }
            float bias = b_pt[col];
#pragma unroll
            for (int i = 0; i < 4; ++i) statsf[(lk * 4 + i) * 64 + col] = aq[i] + bias;
        }
        __syncthreads();
        // ---- P3b: hp = silu(LN(deter @ W_po)) -> stage ----
        dense512<false>(dbf_lds, WpoT, 512, nullptr, g_po, b_po, stage, red, redc, wid, lr, lk);
        __syncthreads();
        // ps = hp @ W_ps + b_ps  (waves 0-3)
        if (wid < 4) {
            f32x4 ap = {};
            int col = wid * 16 + lr;
#pragma unroll 2
            for (int ks = 0; ks < 16; ++ks) {
                short8 a = frag_ld(stage, lr, ks, lk);
                short8 b = *(const short8*)(WpsT + (size_t)col * 512 + ks * 32 + lk * 8);
                ap = mfma16(a, b, ap);
            }
            float bias = b_ps[col];
#pragma unroll
            for (int i = 0; i < 4; ++i) statsf[1024 + (lk * 4 + i) * 64 + col] = ap[i] + bias;
        }
        __syncthreads();
        // ---- P4: outputs + next-step inputs ----
        {
            int row = tid >> 5, c = tid & 31;
            size_t ob = ((size_t)(grow + row) * TT + t) * OUTC;
            float qm = statsf[row * 64 + c];
            float pm = statsf[1024 + row * 64 + c];
            float qr = statsf[row * 64 + 32 + c];
            float pr = statsf[1024 + row * 64 + 32 + c];
            out[ob + c] = qm;
            out[ob + 32 + c] = softplusf_(qr) + MINSTD;
            out[ob + 64 + c] = qm;
            out[ob + 96 + c] = pm;
            out[ob + 128 + c] = softplusf_(pr) + MINSTD;
            if (t + 1 < TT) {
                int f1 = isf[(size_t)(grow + row) * TT + t + 1] > 0;
                if (c == 0) flags[row] = f1;
                *(short*)((char*)a_lds + swz64(row, c)) = f2b(f1 ? sinit[c] : qm);
                float av = (c < ACTN) ? (f1 ? 0.f : action[((size_t)(grow + row) * TT + t + 1) * ACTN + c]) : 0.f;
                *(short*)((char*)a_lds + swz64(row, 32 + c)) = f2b(av);
            }
        }
        __syncthreads();
        if (t + 1 < TT) {
            // deter reset for is_first rows, then next-step prior_in
#pragma unroll
            for (int f = 0; f < 4; ++f) {
                float dv = dinit[c0 + f * 16];
#pragma unroll
                for (int i = 0; i < 4; ++i) {
                    int row = lk * 4 + i;
                    if (flags[row]) {
                        det[f][i] = dv;
                        *(short*)((char*)dbf_lds + swz(row, c0 + f * 16)) = f2b(dv);
                    }
                }
            }
            prior_gemm(a_lds, WpiT, g_pi, b_pi, x_lds, red, redc, wid, lr, lk);
        }
        __syncthreads();
    }
}

// ---- block-wide reduction (k_init only) ----
template <int NV>
__device__ __forceinline__ void breduce(float* v, float* red, int nwaves) {
    __syncthreads();
#pragma unroll
    for (int off = 32; off > 0; off >>= 1)
#pragma unroll
        for (int q = 0; q < NV; ++q) v[q] += __shfl_down(v[q], off);
    int lane = threadIdx.x & 63, w = threadIdx.x >> 6;
    if (lane == 0)
        for (int q = 0; q < NV; ++q) red[w * NV + q] = v[q];
    __syncthreads();
    if ((int)threadIdx.x < NV) {
        float s = 0.f;
        for (int ww = 0; ww < nwaves; ++ww) s += red[ww * NV + threadIdx.x];
        red[nwaves * NV + threadIdx.x] = s;
    }
    __syncthreads();
#pragma unroll
    for (int q = 0; q < NV; ++q) v[q] = red[nwaves * NV + q];
}

__global__ __launch_bounds__(512) void k_init(const float* __restrict__ init_deter, const float* __restrict__ W_po,
                                              const float* __restrict__ g_po, const float* __restrict__ b_po,
                                              const float* __restrict__ W_ps, const float* __restrict__ b_ps,
                                              float* __restrict__ dinit, float* __restrict__ sinit) {
    __shared__ float d_s[512], h_s[512], red[40];
    int tid = threadIdx.x;
    float dv = tanhf(init_deter[tid]);
    d_s[tid] = dv;
    dinit[tid] = dv;
    __syncthreads();
    float acc = 0.f;
    for (int k = 0; k < 512; ++k) acc += d_s[k] * W_po[k * 512 + tid];
    float v[2] = {acc, acc * acc};
    breduce<2>(v, red, 8);
    float m = v[0] / 512.f, va = v[1] / 512.f - m * m, iv = rsqrtf(va + LNEPS);
    h_s[tid] = siluf_((acc - m) * iv * g_po[tid] + b_po[tid]);
    __syncthreads();
    if (tid < 32) {
        float s = b_ps[tid];
        for (int k = 0; k < 512; ++k) s += h_s[k] * W_ps[k * 64 + tid];
        sinit[tid] = s;
    }
}

// ---- prologue: transpose + fp32->bf16: dst[N][K] = src[K][N] ----
__global__ __launch_bounds__(256) void k_transpose_bf(const float* __restrict__ src,
                                                      __hip_bfloat16* __restrict__ dst, int K, int N) {
    __shared__ float tle[32][33];
    int nTK = K >> 5;
    int k0 = (blockIdx.x % nTK) * 32;
    int n0 = (blockIdx.x / nTK) * 32;
    int tx = threadIdx.x & 31, ty = threadIdx.x >> 5;
#pragma unroll
    for (int i = 0; i < 4; ++i) tle[ty + i * 8][tx] = src[(size_t)(k0 + ty + i * 8) * N + n0 + tx];
    __syncthreads();
#pragma unroll
    for (int i = 0; i < 4; ++i)
        dst[(size_t)(n0 + ty + i * 8) * K + k0 + tx] = __float2bfloat16(tle[tx][ty + i * 8]);
}

// ---- prologue: WpiT[512][64] = W_pi[40][512]^T zero-padded to K=64 ----
__global__ __launch_bounds__(256) void k_wpi_pad(const float* __restrict__ W_pi,
                                                 __hip_bfloat16* __restrict__ WpiT) {
    int idx = blockIdx.x * 256 + threadIdx.x;
    if (idx >= 512 * 64) return;
    int n = idx >> 6, k = idx & 63;
    WpiT[idx] = __float2bfloat16(k < CATPI ? W_pi[k * 512 + n] : 0.f);
}

__global__ __launch_bounds__(256) void k_cvt_bf(const float* __restrict__ src, __hip_bfloat16* __restrict__ dst,
                                                int n) {
    for (int i = blockIdx.x * 256 + threadIdx.x; i < n; i += gridDim.x * 256) dst[i] = __float2bfloat16(src[i]);
}

extern "C" void kernel_launch(void* const* d_in, const int* in_sizes, int n_in, void* d_out, int out_size, void* d_ws,
                              size_t ws_size, hipStream_t stream) {
    const float* obs = (const float*)d_in[0];
    const float* action = (const float*)d_in[1];
    const int* is_first = (const int*)d_in[2];
    const float* W_pi = (const float*)d_in[3];
    const float* g_pi = (const float*)d_in[4];
    const float* b_pi = (const float*)d_in[5];
    const float* W_gru = (const float*)d_in[6];
    const float* g_gru = (const float*)d_in[7];
    const float* b_gru = (const float*)d_in[8];
    const float* W_po = (const float*)d_in[9];
    const float* g_po = (const float*)d_in[10];
    const float* b_po = (const float*)d_in[11];
    const float* W_ps = (const float*)d_in[12];
    const float* b_ps = (const float*)d_in[13];
    const float* W_pn = (const float*)d_in[14];
    const float* g_pn = (const float*)d_in[15];
    const float* b_pn = (const float*)d_in[16];
    const float* W_pt = (const float*)d_in[17];
    const float* b_pt = (const float*)d_in[18];
    const float* init_deter = (const float*)d_in[19];
    float* out = (float*)d_out;

    char* p = (char*)d_ws;
    auto alloc = [&](size_t bytes) {
        char* r = p;
        p += (bytes + 255) & ~(size_t)255;
        return r;
    };
    float* dinit = (float*)alloc(512 * 4);
    float* sinit = (float*)alloc(64 * 4);
    __hip_bfloat16* obsbf = (__hip_bfloat16*)alloc((size_t)BB * TT * OBSN * 2);
    __hip_bfloat16* WgT = (__hip_bfloat16*)alloc((size_t)G3N * 1024 * 2);
    __hip_bfloat16* WpoT = (__hip_bfloat16*)alloc((size_t)512 * 512 * 2);
    __hip_bfloat16* WpnT = (__hip_bfloat16*)alloc((size_t)512 * 576 * 2);
    __hip_bfloat16* WpsT = (__hip_bfloat16*)alloc((size_t)64 * 512 * 2);
    __hip_bfloat16* WptT = (__hip_bfloat16*)alloc((size_t)64 * 512 * 2);
    __hip_bfloat16* WpiT = (__hip_bfloat16*)alloc((size_t)512 * 64 * 2);

    k_transpose_bf<<<(1024 / 32) * (G3N / 32), 256, 0, stream>>>(W_gru, WgT, 1024, G3N);
    k_transpose_bf<<<(512 / 32) * (512 / 32), 256, 0, stream>>>(W_po, WpoT, 512, 512);
    k_transpose_bf<<<(576 / 32) * (512 / 32), 256, 0, stream>>>(W_pn, WpnT, 576, 512);
    k_transpose_bf<<<(512 / 32) * (64 / 32), 256, 0, stream>>>(W_ps, WpsT, 512, 64);
    k_transpose_bf<<<(512 / 32) * (64 / 32), 256, 0, stream>>>(W_pt, WptT, 512, 64);
    k_wpi_pad<<<128, 256, 0, stream>>>(W_pi, WpiT);
    k_cvt_bf<<<2048, 256, 0, stream>>>(obs, obsbf, BB * TT * OBSN);
    k_init<<<1, 512, 0, stream>>>(init_deter, W_po, g_po, b_po, W_ps, b_ps, dinit, sinit);

    k_world<<<KWBLK, 512, 0, stream>>>(is_first, action, obsbf, WpiT, g_pi, b_pi, WgT, g_gru, b_gru, WpoT, g_po,
                                       b_po, WpnT, g_pn, b_pn, WpsT, b_ps, WptT, b_pt, dinit, sinit, out);
}

// Round 7
// 4789.420 us; speedup vs baseline: 2.0921x; 2.0921x over previous
//
#include <hip/hip_runtime.h>
#include <hip/hip_bf16.h>
#include <math.h>

#define BB 1024
#define TT 64
#define OBSN 64
#define ACTN 8
#define STOCHN 32
#define DETERN 512
#define HIDN 512
#define G3N 1536
#define CATPI 40
#define OUTC 672
#define LNEPS 1e-3f
#define MINSTD 0.1f
#define UPDBIAS -1.0f

typedef __attribute__((ext_vector_type(8))) short short8;
typedef __attribute__((ext_vector_type(4))) float f32x4;

__device__ __forceinline__ float sigmoidf_(float x) { return 1.f / (1.f + expf(-x)); }
__device__ __forceinline__ float siluf_(float x) { return x / (1.f + expf(-x)); }
__device__ __forceinline__ float softplusf_(float x) { return (x > 20.f) ? x : log1pf(expf(x)); }

__device__ __forceinline__ short f2b(float f) {
    __hip_bfloat16 h = __float2bfloat16(f);
    return __builtin_bit_cast(short, h);
}

__device__ __forceinline__ f32x4 mfma16(short8 a, short8 b, f32x4 c) {
    return __builtin_amdgcn_mfma_f32_16x16x32_bf16(a, b, c, 0, 0, 0);
}

__device__ __forceinline__ void gload_lds16(const void* g, void* l) {
    __builtin_amdgcn_global_load_lds((const __attribute__((address_space(1))) void*)g,
                                     (__attribute__((address_space(3))) void*)l, 16, 0, 0);
}

// ---- swizzled bf16 [16][512] LDS tile: row stride 1024 B, 16B slots XOR'd by row&7 ----
__device__ __forceinline__ int swz(int row, int col) {
    return row * 1024 + ((((col >> 3) ^ (row & 7)) << 4) | ((col & 7) << 1));
}
__device__ __forceinline__ short8 frag_ld(const short* base, int row, int ks, int lk) {
    int slot = (ks * 4 + lk) ^ (row & 7);
    return *(const short8*)((const char*)base + row * 1024 + (slot << 4));
}
// ---- swizzled bf16 [16][64]: row stride 128 B, 8 slots ----
__device__ __forceinline__ int swz64(int row, int col) {
    return row * 128 + (((((col >> 3) ^ (row & 7)) & 7) << 4) | ((col & 7) << 1));
}
__device__ __forceinline__ short8 frag_ld64(const short* base, int row, int ks, int lk) {
    int slot = ((ks * 4 + lk) ^ (row & 7)) & 7;
    return *(const short8*)((const char*)base + row * 128 + (slot << 4));
}

// ---- cross-wave LN combine (8 waves, 16 rows) ----
__device__ __forceinline__ void ln_combine(float s[4], float q[4], float invn, float* red, float* redc, int wid,
                                           int lr, int lk, float m[4], float iv[4]) {
#pragma unroll
    for (int msk = 1; msk <= 8; msk <<= 1)
#pragma unroll
        for (int i = 0; i < 4; ++i) {
            s[i] += __shfl_xor(s[i], msk);
            q[i] += __shfl_xor(q[i], msk);
        }
    if (lr == 0)
#pragma unroll
        for (int i = 0; i < 4; ++i) {
            red[(wid * 16 + lk * 4 + i) * 2 + 0] = s[i];
            red[(wid * 16 + lk * 4 + i) * 2 + 1] = q[i];
        }
    __syncthreads();
    int tid = threadIdx.x;
    if (tid < 32) {
        int row = tid >> 1, v = tid & 1;
        float a = 0.f;
#pragma unroll
        for (int w = 0; w < 8; ++w) a += red[(w * 16 + row) * 2 + v];
        redc[row * 2 + v] = a;
    }
    __syncthreads();
#pragma unroll
    for (int i = 0; i < 4; ++i) {
        int row = lk * 4 + i;
        float mm = redc[row * 2] * invn;
        float vv = redc[row * 2 + 1] * invn - mm * mm;
        m[i] = mm;
        iv[i] = rsqrtf(vv + LNEPS);
    }
}

// ---- dense 16xK @ Wt[N=512][K]^T -> LN -> silu -> bf16 swizzled dst (8 waves, 64 cols each) ----
template <bool OBS_TAIL>
__device__ __forceinline__ void dense512(const short* A_lds, const __hip_bfloat16* Wt, int ldw,
                                         const __hip_bfloat16* op, const float* gg, const float* bb, short* dst,
                                         float* red, float* redc, int wid, int lr, int lk) {
    f32x4 acc[4] = {};
    const int c0 = wid * 64 + lr;
#pragma unroll 2
    for (int ks = 0; ks < 16; ++ks) {
        short8 a = frag_ld(A_lds, lr, ks, lk);
#pragma unroll
        for (int f = 0; f < 4; ++f) {
            short8 b = *(const short8*)(Wt + (size_t)(c0 + f * 16) * ldw + ks * 32 + lk * 8);
            acc[f] = mfma16(a, b, acc[f]);
        }
    }
    if constexpr (OBS_TAIL) {
#pragma unroll
        for (int ks = 0; ks < 2; ++ks) {
            short8 a = *(const short8*)(op + ks * 32 + lk * 8);
#pragma unroll
            for (int f = 0; f < 4; ++f) {
                short8 b = *(const short8*)(Wt + (size_t)(c0 + f * 16) * ldw + 512 + ks * 32 + lk * 8);
                acc[f] = mfma16(a, b, acc[f]);
            }
        }
    }
    float s[4] = {}, q[4] = {};
#pragma unroll
    for (int f = 0; f < 4; ++f)
#pragma unroll
        for (int i = 0; i < 4; ++i) {
            float v = acc[f][i];
            s[i] += v;
            q[i] += v * v;
        }
    float m[4], iv[4];
    ln_combine(s, q, 1.f / 512.f, red, redc, wid, lr, lk, m, iv);
#pragma unroll
    for (int f = 0; f < 4; ++f) {
        int col = c0 + f * 16;
        float g = gg[col], b = bb[col];
#pragma unroll
        for (int i = 0; i < 4; ++i) {
            float v = siluf_((acc[f][i] - m[i]) * iv[i] * g + b);
            *(short*)((char*)dst + swz(lk * 4 + i, col)) = f2b(v);
        }
    }
}

// ---- prior_in: x = silu(LN(a[16x64] @ WpiT[512][64]^T)) -> xbf global ----
__device__ __forceinline__ void prior_gemm(const short* a_lds, const __hip_bfloat16* WpiT, const float* g_pi,
                                           const float* b_pi, __hip_bfloat16* xbf, int grow, float* red,
                                           float* redc, int wid, int lr, int lk) {
    f32x4 acc[4] = {};
    const int c0 = wid * 64 + lr;
#pragma unroll
    for (int ks = 0; ks < 2; ++ks) {
        short8 a = frag_ld64(a_lds, lr, ks, lk);
#pragma unroll
        for (int f = 0; f < 4; ++f) {
            short8 b = *(const short8*)(WpiT + (size_t)(c0 + f * 16) * 64 + ks * 32 + lk * 8);
            acc[f] = mfma16(a, b, acc[f]);
        }
    }
    float s[4] = {}, q[4] = {};
#pragma unroll
    for (int f = 0; f < 4; ++f)
#pragma unroll
        for (int i = 0; i < 4; ++i) {
            float v = acc[f][i];
            s[i] += v;
            q[i] += v * v;
        }
    float m[4], iv[4];
    ln_combine(s, q, 1.f / 512.f, red, redc, wid, lr, lk, m, iv);
#pragma unroll
    for (int f = 0; f < 4; ++f) {
        int col = c0 + f * 16;
        float g = g_pi[col], b = b_pi[col];
#pragma unroll
        for (int i = 0; i < 4; ++i) {
            float v = siluf_((acc[f][i] - m[i]) * iv[i] * g + b);
            xbf[(size_t)(grow + lk * 4 + i) * 512 + col] = __float2bfloat16(v);
        }
    }
}

// ==== K1: GRU GEMM, 256 blocks of 64x96 (validated round-4 double-buffered core) ====
template <int NFC>
__device__ __forceinline__ void stage_tile(const __hip_bfloat16* A0, int ld0, int K0, const __hip_bfloat16* A1,
                                           int ld1, const __hip_bfloat16* Wt, int ldW, int wn0, int cm0, int k0,
                                           char* smA, char* smB) {
    int tid = threadIdx.x, wid = tid >> 6, lane = tid & 63;
    int rseg = lane >> 3, slot = lane & 7;
    const __hip_bfloat16* Ab;
    int ldA, kloc;
    if (k0 < K0) {
        Ab = A0; ldA = ld0; kloc = k0;
    } else {
        Ab = A1; ldA = ld1; kloc = k0 - K0;
    }
#pragma unroll
    for (int i = 0; i < 2; ++i) {
        int seg = wid * 2 + i;
        int row = seg * 8 + rseg;
        int kk = kloc + ((slot ^ (row & 7)) << 3);
        gload_lds16(Ab + (size_t)(cm0 + row) * ldA + kk, smA + seg * 1024);
    }
#pragma unroll
    for (int i = 0; i < NFC; ++i) {
        int seg = wid * NFC + i;
        int row = seg * 8 + rseg;
        int kk = k0 + ((slot ^ (row & 7)) << 3);
        gload_lds16(Wt + (size_t)(wn0 + row) * ldW + kk, smB + seg * 1024);
    }
}

template <int NFC>
__device__ __forceinline__ void compute_tile(const char* smA, const char* smB, f32x4 (&acc)[2][NFC]) {
    int lane = threadIdx.x & 63, wid = threadIdx.x >> 6;
    int wr = wid >> 1, wc = wid & 1;
#pragma unroll
    for (int ks = 0; ks < 2; ++ks) {
        short8 af[2], bfr[NFC];
        int kslot = ks * 4 + (lane >> 4);
#pragma unroll
        for (int m = 0; m < 2; ++m) {
            int row = wr * 32 + m * 16 + (lane & 15);
            af[m] = *(const short8*)(smA + row * 128 + ((kslot ^ (row & 7)) << 4));
        }
#pragma unroll
        for (int n = 0; n < NFC; ++n) {
            int row = wc * (16 * NFC) + n * 16 + (lane & 15);
            bfr[n] = *(const short8*)(smB + row * 128 + ((kslot ^ (row & 7)) << 4));
        }
#pragma unroll
        for (int m = 0; m < 2; ++m)
#pragma unroll
            for (int n = 0; n < NFC; ++n)
                acc[m][n] = mfma16(af[m], bfr[n], acc[m][n]);
    }
}

template <int NFC>
__device__ __forceinline__ void gemm_tile_db(const __hip_bfloat16* A0, int ld0, int K0, const __hip_bfloat16* A1,
                                             int ld1, const __hip_bfloat16* Wt, int ldW, int wn0, float* C, int ldc,
                                             int cm0, int cn0, int nK, char* smem) {
    char* smA[2] = {smem, smem + 8192};
    char* smB[2] = {smem + 16384, smem + 16384 + NFC * 4096};
    f32x4 acc[2][NFC] = {};
    stage_tile<NFC>(A0, ld0, K0, A1, ld1, Wt, ldW, wn0, cm0, 0, smA[0], smB[0]);
    for (int kt = 0; kt < nK; ++kt) {
        if (kt + 1 < nK) {
            stage_tile<NFC>(A0, ld0, K0, A1, ld1, Wt, ldW, wn0, cm0, (kt + 1) * 64, smA[(kt + 1) & 1],
                            smB[(kt + 1) & 1]);
            if constexpr (NFC == 3) asm volatile("s_waitcnt vmcnt(5)" ::: "memory");
            else asm volatile("s_waitcnt vmcnt(4)" ::: "memory");
        } else {
            asm volatile("s_waitcnt vmcnt(0)" ::: "memory");
        }
        __builtin_amdgcn_s_barrier();
        compute_tile<NFC>(smA[kt & 1], smB[kt & 1], acc);
        __builtin_amdgcn_s_barrier();
    }
    int lane = threadIdx.x & 63, wid = threadIdx.x >> 6;
    int wr = wid >> 1, wc = wid & 1;
    int r0 = cm0 + wr * 32 + ((lane >> 4) << 2);
    int c0 = cn0 + wc * 16 * NFC + (lane & 15);
#pragma unroll
    for (int m = 0; m < 2; ++m)
#pragma unroll
        for (int n = 0; n < NFC; ++n)
#pragma unroll
            for (int i = 0; i < 4; ++i)
                C[(size_t)(r0 + m * 16 + i) * ldc + c0 + n * 16] = acc[m][n][i];
}

__global__ __launch_bounds__(256) void k_gemm_gru(const __hip_bfloat16* __restrict__ xbf,
                                                  const __hip_bfloat16* __restrict__ dbf,
                                                  const __hip_bfloat16* __restrict__ WgT,
                                                  float* __restrict__ gates) {
    __shared__ __align__(16) char smem[40960];
    int bm = blockIdx.x & 15, bn = blockIdx.x >> 4;
    gemm_tile_db<3>(xbf, 512, 512, dbf, 512, WgT, 1024, bn * 96, gates, G3N, bm * 64, bn * 96, 16, smem);
}

// ==== K2: fused LN/update + h-GEMMs + stats + outputs + next-step prior_in ====
// 64 blocks x 512 threads; block owns 16 batch rows.
__global__ __launch_bounds__(512) void k_step2(
    int t, const float* __restrict__ gates, float* __restrict__ deter, __hip_bfloat16* __restrict__ dbf,
    __hip_bfloat16* __restrict__ xbf, const __hip_bfloat16* __restrict__ obsbf, const int* __restrict__ isf,
    const float* __restrict__ action, const float* __restrict__ g_gru, const float* __restrict__ b_gru,
    const __hip_bfloat16* __restrict__ WpoT, const float* __restrict__ g_po, const float* __restrict__ b_po,
    const __hip_bfloat16* __restrict__ WpnT, const float* __restrict__ g_pn, const float* __restrict__ b_pn,
    const __hip_bfloat16* __restrict__ WpsT, const float* __restrict__ b_ps,
    const __hip_bfloat16* __restrict__ WptT, const float* __restrict__ b_pt,
    const __hip_bfloat16* __restrict__ WpiT, const float* __restrict__ g_pi, const float* __restrict__ b_pi,
    const float* __restrict__ dinit, const float* __restrict__ sinit, float* __restrict__ out) {
    __shared__ short dn_lds[16 * 512];
    __shared__ short stage[16 * 512];
    __shared__ short a_lds[16 * 64];
    __shared__ float statsf[2 * 16 * 64];
    __shared__ float red[8 * 16 * 2];
    __shared__ float redc[16 * 2];
    __shared__ int flags[16];

    const int tid = threadIdx.x, wid = tid >> 6, lane = tid & 63, lr = lane & 15, lk = lane >> 4;
    const int grow = blockIdx.x * 16;
    const int prow = tid >> 5, pc = tid & 31;  // 16 rows x 32 threads
    const int gr = grow + prow;
    const int j0 = pc * 16;

    // ---- phase 1: LN(gates) + GRU update -> deter (global), dbf (global), dn_lds, out ----
    {
        const float* gp = gates + (size_t)gr * G3N;
        float g0[16], g1[16], g2[16];
        float s = 0.f, q = 0.f;
#pragma unroll
        for (int e = 0; e < 16; e += 4) {
            f32x4 a = *(const f32x4*)(gp + j0 + e);
            f32x4 b = *(const f32x4*)(gp + 512 + j0 + e);
            f32x4 c = *(const f32x4*)(gp + 1024 + j0 + e);
#pragma unroll
            for (int u = 0; u < 4; ++u) {
                g0[e + u] = a[u];
                g1[e + u] = b[u];
                g2[e + u] = c[u];
                s += a[u] + b[u] + c[u];
                q += a[u] * a[u] + b[u] * b[u] + c[u] * c[u];
            }
        }
#pragma unroll
        for (int msk = 1; msk <= 16; msk <<= 1) {
            s += __shfl_xor(s, msk);
            q += __shfl_xor(q, msk);
        }
        float m = s * (1.f / 1536.f), iv = rsqrtf(q * (1.f / 1536.f) - m * m + LNEPS);
        float dn[16];
        float* dp = deter + (size_t)gr * 512 + j0;
#pragma unroll
        for (int e = 0; e < 16; e += 4) {
            f32x4 dv = *(const f32x4*)(dp + e);
#pragma unroll
            for (int u = 0; u < 4; ++u) {
                int col = j0 + e + u;
                float rv = sigmoidf_((g0[e + u] - m) * iv * g_gru[col] + b_gru[col]);
                float cv = (g1[e + u] - m) * iv * g_gru[512 + col] + b_gru[512 + col];
                float uv = sigmoidf_((g2[e + u] - m) * iv * g_gru[1024 + col] + b_gru[1024 + col] + UPDBIAS);
                dn[e + u] = uv * siluf_(rv * cv) + (1.f - uv) * dv[u];
            }
        }
        size_t ob = ((size_t)gr * TT + t) * OUTC + 160 + j0;
        short8 h0, h1;
#pragma unroll
        for (int e = 0; e < 16; e += 4) {
            *(f32x4*)(dp + e) = *(const f32x4*)&dn[e];
            *(f32x4*)(out + ob + e) = *(const f32x4*)&dn[e];
        }
#pragma unroll
        for (int u = 0; u < 8; ++u) {
            h0[u] = f2b(dn[u]);
            h1[u] = f2b(dn[8 + u]);
        }
        *(short8*)(dbf + (size_t)gr * 512 + j0) = h0;
        *(short8*)(dbf + (size_t)gr * 512 + j0 + 8) = h1;
        *(short8*)((char*)dn_lds + swz(prow, j0)) = h0;
        *(short8*)((char*)dn_lds + swz(prow, j0 + 8)) = h1;
    }
    __syncthreads();
    // ---- hq = silu(LN(cat(deter_n, obs_t) @ W_pn)) ----
    {
        const __hip_bfloat16* op = obsbf + ((size_t)(grow + lr) * TT + t) * OBSN;
        dense512<true>(dn_lds, WpnT, 576, op, g_pn, b_pn, stage, red, redc, wid, lr, lk);
    }
    __syncthreads();
    if (wid < 4) {  // qs = hq @ W_pt + b_pt
        f32x4 aq = {};
        int col = wid * 16 + lr;
#pragma unroll 2
        for (int ks = 0; ks < 16; ++ks) {
            short8 a = frag_ld(stage, lr, ks, lk);
            short8 b = *(const short8*)(WptT + (size_t)col * 512 + ks * 32 + lk * 8);
            aq = mfma16(a, b, aq);
        }
        float bias = b_pt[col];
#pragma unroll
        for (int i = 0; i < 4; ++i) statsf[(lk * 4 + i) * 64 + col] = aq[i] + bias;
    }
    __syncthreads();
    // ---- hp = silu(LN(deter_n @ W_po)) ----
    dense512<false>(dn_lds, WpoT, 512, nullptr, g_po, b_po, stage, red, redc, wid, lr, lk);
    __syncthreads();
    if (wid < 4) {  // ps = hp @ W_ps + b_ps
        f32x4 ap = {};
        int col = wid * 16 + lr;
#pragma unroll 2
        for (int ks = 0; ks < 16; ++ks) {
            short8 a = frag_ld(stage, lr, ks, lk);
            short8 b = *(const short8*)(WpsT + (size_t)col * 512 + ks * 32 + lk * 8);
            ap = mfma16(a, b, ap);
        }
        float bias = b_ps[col];
#pragma unroll
        for (int i = 0; i < 4; ++i) statsf[1024 + (lk * 4 + i) * 64 + col] = ap[i] + bias;
    }
    __syncthreads();
    // ---- P4: stats outputs + next-step inputs ----
    {
        size_t ob = ((size_t)gr * TT + t) * OUTC;
        if (pc < 32) {
            float qm = statsf[prow * 64 + pc];
            float pm = statsf[1024 + prow * 64 + pc];
            float qr = statsf[prow * 64 + 32 + pc];
            float pr = statsf[1024 + prow * 64 + 32 + pc];
            out[ob + pc] = qm;
            out[ob + 32 + pc] = softplusf_(qr) + MINSTD;
            out[ob + 64 + pc] = qm;
            out[ob + 96 + pc] = pm;
            out[ob + 128 + pc] = softplusf_(pr) + MINSTD;
            if (t + 1 < TT) {
                int f1 = isf[(size_t)gr * TT + t + 1] > 0;
                if (pc == 0) flags[prow] = f1;
                *(short*)((char*)a_lds + swz64(prow, pc)) = f2b(f1 ? sinit[pc] : qm);
                float av = (pc < ACTN) ? (f1 ? 0.f : action[((size_t)gr * TT + t + 1) * ACTN + pc]) : 0.f;
                *(short*)((char*)a_lds + swz64(prow, 32 + pc)) = f2b(av);
            }
        }
    }
    if (t + 1 >= TT) return;
    __syncthreads();
    // deter reset for is_first rows (next step state)
    if (flags[prow]) {
        short8 h0, h1;
#pragma unroll
        for (int e = 0; e < 16; e += 4) *(f32x4*)(deter + (size_t)gr * 512 + j0 + e) = *(const f32x4*)(dinit + j0 + e);
#pragma unroll
        for (int u = 0; u < 8; ++u) {
            h0[u] = f2b(dinit[j0 + u]);
            h1[u] = f2b(dinit[j0 + 8 + u]);
        }
        *(short8*)(dbf + (size_t)gr * 512 + j0) = h0;
        *(short8*)(dbf + (size_t)gr * 512 + j0 + 8) = h1;
    }
    __syncthreads();
    prior_gemm(a_lds, WpiT, g_pi, b_pi, xbf, grow, red, redc, wid, lr, lk);
}

// ==== t=0 state + first prior_in ====
__global__ __launch_bounds__(512) void k_prior0(const int* __restrict__ isf, const float* __restrict__ action,
                                                const float* __restrict__ dinit, const float* __restrict__ sinit,
                                                const __hip_bfloat16* __restrict__ WpiT,
                                                const float* __restrict__ g_pi, const float* __restrict__ b_pi,
                                                float* __restrict__ deter, __hip_bfloat16* __restrict__ dbf,
                                                __hip_bfloat16* __restrict__ xbf) {
    __shared__ short a_lds[16 * 64];
    __shared__ float red[8 * 16 * 2];
    __shared__ float redc[16 * 2];
    const int tid = threadIdx.x, wid = tid >> 6, lane = tid & 63, lr = lane & 15, lk = lane >> 4;
    const int grow = blockIdx.x * 16;
    const int prow = tid >> 5, pc = tid & 31;
    const int gr = grow + prow;
    const int j0 = pc * 16;
    {
        int f0 = isf[(size_t)gr * TT] > 0;
        if (pc < 32) {
            *(short*)((char*)a_lds + swz64(prow, pc)) = f2b(sinit[pc]);
            float av = (pc < ACTN) ? (f0 ? 0.f : action[(size_t)gr * TT * ACTN + pc]) : 0.f;
            *(short*)((char*)a_lds + swz64(prow, 32 + pc)) = f2b(av);
        }
        short8 h0, h1;
#pragma unroll
        for (int e = 0; e < 16; e += 4) *(f32x4*)(deter + (size_t)gr * 512 + j0 + e) = *(const f32x4*)(dinit + j0 + e);
#pragma unroll
        for (int u = 0; u < 8; ++u) {
            h0[u] = f2b(dinit[j0 + u]);
            h1[u] = f2b(dinit[j0 + 8 + u]);
        }
        *(short8*)(dbf + (size_t)gr * 512 + j0) = h0;
        *(short8*)(dbf + (size_t)gr * 512 + j0 + 8) = h1;
    }
    __syncthreads();
    prior_gemm(a_lds, WpiT, g_pi, b_pi, xbf, grow, red, redc, wid, lr, lk);
}

// ---- block-wide reduction (k_init only) ----
template <int NV>
__device__ __forceinline__ void breduce(float* v, float* red, int nwaves) {
    __syncthreads();
#pragma unroll
    for (int off = 32; off > 0; off >>= 1)
#pragma unroll
        for (int q = 0; q < NV; ++q) v[q] += __shfl_down(v[q], off);
    int lane = threadIdx.x & 63, w = threadIdx.x >> 6;
    if (lane == 0)
        for (int q = 0; q < NV; ++q) red[w * NV + q] = v[q];
    __syncthreads();
    if ((int)threadIdx.x < NV) {
        float s = 0.f;
        for (int ww = 0; ww < nwaves; ++ww) s += red[ww * NV + threadIdx.x];
        red[nwaves * NV + threadIdx.x] = s;
    }
    __syncthreads();
#pragma unroll
    for (int q = 0; q < NV; ++q) v[q] = red[nwaves * NV + q];
}

__global__ __launch_bounds__(512) void k_init(const float* __restrict__ init_deter, const float* __restrict__ W_po,
                                              const float* __restrict__ g_po, const float* __restrict__ b_po,
                                              const float* __restrict__ W_ps, const float* __restrict__ b_ps,
                                              float* __restrict__ dinit, float* __restrict__ sinit) {
    __shared__ float d_s[512], h_s[512], red[40];
    int tid = threadIdx.x;
    float dv = tanhf(init_deter[tid]);
    d_s[tid] = dv;
    dinit[tid] = dv;
    __syncthreads();
    float acc = 0.f;
    for (int k = 0; k < 512; ++k) acc += d_s[k] * W_po[k * 512 + tid];
    float v[2] = {acc, acc * acc};
    breduce<2>(v, red, 8);
    float m = v[0] / 512.f, va = v[1] / 512.f - m * m, iv = rsqrtf(va + LNEPS);
    h_s[tid] = siluf_((acc - m) * iv * g_po[tid] + b_po[tid]);
    __syncthreads();
    if (tid < 32) {
        float s = b_ps[tid];
        for (int k = 0; k < 512; ++k) s += h_s[k] * W_ps[k * 64 + tid];
        sinit[tid] = s;
    }
}

__global__ __launch_bounds__(256) void k_transpose_bf(const float* __restrict__ src,
                                                      __hip_bfloat16* __restrict__ dst, int K, int N) {
    __shared__ float tle[32][33];
    int nTK = K >> 5;
    int k0 = (blockIdx.x % nTK) * 32;
    int n0 = (blockIdx.x / nTK) * 32;
    int tx = threadIdx.x & 31, ty = threadIdx.x >> 5;
#pragma unroll
    for (int i = 0; i < 4; ++i) tle[ty + i * 8][tx] = src[(size_t)(k0 + ty + i * 8) * N + n0 + tx];
    __syncthreads();
#pragma unroll
    for (int i = 0; i < 4; ++i)
        dst[(size_t)(n0 + ty + i * 8) * K + k0 + tx] = __float2bfloat16(tle[tx][ty + i * 8]);
}

__global__ __launch_bounds__(256) void k_wpi_pad(const float* __restrict__ W_pi,
                                                 __hip_bfloat16* __restrict__ WpiT) {
    int idx = blockIdx.x * 256 + threadIdx.x;
    if (idx >= 512 * 64) return;
    int n = idx >> 6, k = idx & 63;
    WpiT[idx] = __float2bfloat16(k < CATPI ? W_pi[k * 512 + n] : 0.f);
}

__global__ __launch_bounds__(256) void k_cvt_bf(const float* __restrict__ src, __hip_bfloat16* __restrict__ dst,
                                                int n) {
    for (int i = blockIdx.x * 256 + threadIdx.x; i < n; i += gridDim.x * 256) dst[i] = __float2bfloat16(src[i]);
}

extern "C" void kernel_launch(void* const* d_in, const int* in_sizes, int n_in, void* d_out, int out_size, void* d_ws,
                              size_t ws_size, hipStream_t stream) {
    const float* obs = (const float*)d_in[0];
    const float* action = (const float*)d_in[1];
    const int* is_first = (const int*)d_in[2];
    const float* W_pi = (const float*)d_in[3];
    const float* g_pi = (const float*)d_in[4];
    const float* b_pi = (const float*)d_in[5];
    const float* W_gru = (const float*)d_in[6];
    const float* g_gru = (const float*)d_in[7];
    const float* b_gru = (const float*)d_in[8];
    const float* W_po = (const float*)d_in[9];
    const float* g_po = (const float*)d_in[10];
    const float* b_po = (const float*)d_in[11];
    const float* W_ps = (const float*)d_in[12];
    const float* b_ps = (const float*)d_in[13];
    const float* W_pn = (const float*)d_in[14];
    const float* g_pn = (const float*)d_in[15];
    const float* b_pn = (const float*)d_in[16];
    const float* W_pt = (const float*)d_in[17];
    const float* b_pt = (const float*)d_in[18];
    const float* init_deter = (const float*)d_in[19];
    float* out = (float*)d_out;

    char* p = (char*)d_ws;
    auto alloc = [&](size_t bytes) {
        char* r = p;
        p += (bytes + 255) & ~(size_t)255;
        return r;
    };
    float* gates = (float*)alloc((size_t)BB * G3N * 4);
    float* deter = (float*)alloc((size_t)BB * 512 * 4);
    float* dinit = (float*)alloc(512 * 4);
    float* sinit = (float*)alloc(64 * 4);
    __hip_bfloat16* xbf = (__hip_bfloat16*)alloc((size_t)BB * 512 * 2);
    __hip_bfloat16* dbf = (__hip_bfloat16*)alloc((size_t)BB * 512 * 2);
    __hip_bfloat16* obsbf = (__hip_bfloat16*)alloc((size_t)BB * TT * OBSN * 2);
    __hip_bfloat16* WgT = (__hip_bfloat16*)alloc((size_t)G3N * 1024 * 2);
    __hip_bfloat16* WpoT = (__hip_bfloat16*)alloc((size_t)512 * 512 * 2);
    __hip_bfloat16* WpnT = (__hip_bfloat16*)alloc((size_t)512 * 576 * 2);
    __hip_bfloat16* WpsT = (__hip_bfloat16*)alloc((size_t)64 * 512 * 2);
    __hip_bfloat16* WptT = (__hip_bfloat16*)alloc((size_t)64 * 512 * 2);
    __hip_bfloat16* WpiT = (__hip_bfloat16*)alloc((size_t)512 * 64 * 2);

    k_transpose_bf<<<(1024 / 32) * (G3N / 32), 256, 0, stream>>>(W_gru, WgT, 1024, G3N);
    k_transpose_bf<<<(512 / 32) * (512 / 32), 256, 0, stream>>>(W_po, WpoT, 512, 512);
    k_transpose_bf<<<(576 / 32) * (512 / 32), 256, 0, stream>>>(W_pn, WpnT, 576, 512);
    k_transpose_bf<<<(512 / 32) * (64 / 32), 256, 0, stream>>>(W_ps, WpsT, 512, 64);
    k_transpose_bf<<<(512 / 32) * (64 / 32), 256, 0, stream>>>(W_pt, WptT, 512, 64);
    k_wpi_pad<<<128, 256, 0, stream>>>(W_pi, WpiT);
    k_cvt_bf<<<2048, 256, 0, stream>>>(obs, obsbf, BB * TT * OBSN);
    k_init<<<1, 512, 0, stream>>>(init_deter, W_po, g_po, b_po, W_ps, b_ps, dinit, sinit);
    k_prior0<<<64, 512, 0, stream>>>(is_first, action, dinit, sinit, WpiT, g_pi, b_pi, deter, dbf, xbf);

    for (int t = 0; t < TT; ++t) {
        k_gemm_gru<<<256, 256, 0, stream>>>(xbf, dbf, WgT, gates);
        k_step2<<<64, 512, 0, stream>>>(t, gates, deter, dbf, xbf, obsbf, is_first, action, g_gru, b_gru, WpoT,
                                        g_po, b_po, WpnT, g_pn, b_pn, WpsT, b_ps, WptT, b_pt, WpiT, g_pi, b_pi,
                                        dinit, sinit, out);
    }
}

// Round 8
// 4208.959 us; speedup vs baseline: 2.3806x; 1.1379x over previous
//
#include <hip/hip_runtime.h>
#include <hip/hip_bf16.h>
#include <math.h>

#define BB 1024
#define TT 64
#define OBSN 64
#define ACTN 8
#define STOCHN 32
#define DETERN 512
#define HIDN 512
#define G3N 1536
#define CATPI 40
#define OUTC 672
#define LNEPS 1e-3f
#define MINSTD 0.1f
#define UPDBIAS -1.0f

typedef __attribute__((ext_vector_type(8))) short short8;
typedef __attribute__((ext_vector_type(4))) float f32x4;

__device__ __forceinline__ float sigmoidf_(float x) { return 1.f / (1.f + expf(-x)); }
__device__ __forceinline__ float siluf_(float x) { return x / (1.f + expf(-x)); }
__device__ __forceinline__ float softplusf_(float x) { return (x > 20.f) ? x : log1pf(expf(x)); }

__device__ __forceinline__ short f2b(float f) {
    __hip_bfloat16 h = __float2bfloat16(f);
    return __builtin_bit_cast(short, h);
}

__device__ __forceinline__ f32x4 mfma16(short8 a, short8 b, f32x4 c) {
    return __builtin_amdgcn_mfma_f32_16x16x32_bf16(a, b, c, 0, 0, 0);
}

__device__ __forceinline__ void gload_lds16(const void* g, void* l) {
    __builtin_amdgcn_global_load_lds((const __attribute__((address_space(1))) void*)g,
                                     (__attribute__((address_space(3))) void*)l, 16, 0, 0);
}

// ---- swizzled bf16 [16][512] LDS tile: row stride 1024 B, 16B slots XOR'd by row&7 ----
__device__ __forceinline__ int swz(int row, int col) {
    return row * 1024 + ((((col >> 3) ^ (row & 7)) << 4) | ((col & 7) << 1));
}
__device__ __forceinline__ short8 frag_ld(const short* base, int row, int ks, int lk) {
    int slot = (ks * 4 + lk) ^ (row & 7);
    return *(const short8*)((const char*)base + row * 1024 + (slot << 4));
}
// ---- swizzled bf16 rows of 64 cols (128 B stride): works for [16][64] and [512][64] ----
__device__ __forceinline__ int swz64(int row, int col) {
    return row * 128 + (((((col >> 3) ^ (row & 7)) & 7) << 4) | ((col & 7) << 1));
}
__device__ __forceinline__ short8 frag_ld64(const short* base, int row, int ks, int lk) {
    int slot = ((ks * 4 + lk) ^ (row & 7)) & 7;
    return *(const short8*)((const char*)base + row * 128 + (slot << 4));
}

// ---- cross-wave LN combine (8 waves, 16 rows) ----
__device__ __forceinline__ void ln_combine(float s[4], float q[4], float invn, float* red, float* redc, int wid,
                                           int lr, int lk, float m[4], float iv[4]) {
#pragma unroll
    for (int msk = 1; msk <= 8; msk <<= 1)
#pragma unroll
        for (int i = 0; i < 4; ++i) {
            s[i] += __shfl_xor(s[i], msk);
            q[i] += __shfl_xor(q[i], msk);
        }
    if (lr == 0)
#pragma unroll
        for (int i = 0; i < 4; ++i) {
            red[(wid * 16 + lk * 4 + i) * 2 + 0] = s[i];
            red[(wid * 16 + lk * 4 + i) * 2 + 1] = q[i];
        }
    __syncthreads();
    int tid = threadIdx.x;
    if (tid < 32) {
        int row = tid >> 1, v = tid & 1;
        float a = 0.f;
#pragma unroll
        for (int w = 0; w < 8; ++w) a += red[(w * 16 + row) * 2 + v];
        redc[row * 2 + v] = a;
    }
    __syncthreads();
#pragma unroll
    for (int i = 0; i < 4; ++i) {
        int row = lk * 4 + i;
        float mm = redc[row * 2] * invn;
        float vv = redc[row * 2 + 1] * invn - mm * mm;
        m[i] = mm;
        iv[i] = rsqrtf(vv + LNEPS);
    }
}

// ---- STAGED dense 16xK @ Wt[N=512][K]^T -> LN -> silu -> bf16 swizzled dst.
// B streamed through 64KB LDS chunks ([512 rows][64 K], row stride 128B) via global_load_lds.
template <bool OBS_TAIL>
__device__ __forceinline__ void dense512_staged(const short* A_lds, const __hip_bfloat16* Wt, int ldw,
                                                const __hip_bfloat16* op, const float* gg, const float* bb,
                                                short* dst, short* Bbuf, float* red, float* redc, int wid, int lr,
                                                int lk) {
    f32x4 acc[4] = {};
    const int c0 = wid * 64 + lr;
    const int lane = threadIdx.x & 63;
    const int rseg = lane >> 3, slot = lane & 7;
    const int NCH = OBS_TAIL ? 9 : 8;
    for (int ck = 0; ck < NCH; ++ck) {
        // cooperative stage: 64 segs of 8 rows; each thread 8x16B async
#pragma unroll
        for (int i = 0; i < 8; ++i) {
            int seg = wid * 8 + i;
            int row = seg * 8 + rseg;
            int kk = ck * 64 + ((slot ^ (row & 7)) << 3);
            gload_lds16(Wt + (size_t)row * ldw + kk, (char*)Bbuf + seg * 1024);
        }
        asm volatile("s_waitcnt vmcnt(0)" ::: "memory");
        __builtin_amdgcn_s_barrier();
        if (ck < 8) {
#pragma unroll
            for (int ks = 0; ks < 2; ++ks) {
                short8 a = frag_ld(A_lds, lr, ck * 2 + ks, lk);
#pragma unroll
                for (int f = 0; f < 4; ++f) acc[f] = mfma16(a, frag_ld64(Bbuf, c0 + f * 16, ks, lk), acc[f]);
            }
        } else {  // obs tail: A-fragment direct from global obs row
#pragma unroll
            for (int ks = 0; ks < 2; ++ks) {
                short8 a = *(const short8*)(op + ks * 32 + lk * 8);
#pragma unroll
                for (int f = 0; f < 4; ++f) acc[f] = mfma16(a, frag_ld64(Bbuf, c0 + f * 16, ks, lk), acc[f]);
            }
        }
        __builtin_amdgcn_s_barrier();
    }
    float s[4] = {}, q[4] = {};
#pragma unroll
    for (int f = 0; f < 4; ++f)
#pragma unroll
        for (int i = 0; i < 4; ++i) {
            float v = acc[f][i];
            s[i] += v;
            q[i] += v * v;
        }
    float m[4], iv[4];
    ln_combine(s, q, 1.f / 512.f, red, redc, wid, lr, lk, m, iv);
#pragma unroll
    for (int f = 0; f < 4; ++f) {
        int col = c0 + f * 16;
        float g = gg[col], b = bb[col];
#pragma unroll
        for (int i = 0; i < 4; ++i) {
            float v = siluf_((acc[f][i] - m[i]) * iv[i] * g + b);
            *(short*)((char*)dst + swz(lk * 4 + i, col)) = f2b(v);
        }
    }
}

// ---- prior_in: x = silu(LN(a[16x64] @ WpiT[512][64]^T)) -> xbf global ----
__device__ __forceinline__ void prior_gemm(const short* a_lds, const __hip_bfloat16* WpiT, const float* g_pi,
                                           const float* b_pi, __hip_bfloat16* xbf, int grow, float* red,
                                           float* redc, int wid, int lr, int lk) {
    f32x4 acc[4] = {};
    const int c0 = wid * 64 + lr;
#pragma unroll
    for (int ks = 0; ks < 2; ++ks) {
        short8 a = frag_ld64(a_lds, lr, ks, lk);
#pragma unroll
        for (int f = 0; f < 4; ++f) {
            short8 b = *(const short8*)(WpiT + (size_t)(c0 + f * 16) * 64 + ks * 32 + lk * 8);
            acc[f] = mfma16(a, b, acc[f]);
        }
    }
    float s[4] = {}, q[4] = {};
#pragma unroll
    for (int f = 0; f < 4; ++f)
#pragma unroll
        for (int i = 0; i < 4; ++i) {
            float v = acc[f][i];
            s[i] += v;
            q[i] += v * v;
        }
    float m[4], iv[4];
    ln_combine(s, q, 1.f / 512.f, red, redc, wid, lr, lk, m, iv);
#pragma unroll
    for (int f = 0; f < 4; ++f) {
        int col = c0 + f * 16;
        float g = g_pi[col], b = b_pi[col];
#pragma unroll
        for (int i = 0; i < 4; ++i) {
            float v = siluf_((acc[f][i] - m[i]) * iv[i] * g + b);
            xbf[(size_t)(grow + lk * 4 + i) * 512 + col] = __float2bfloat16(v);
        }
    }
}

// ==== K1: GRU GEMM, 256 blocks of 64x96 (validated double-buffered core) ====
template <int NFC>
__device__ __forceinline__ void stage_tile(const __hip_bfloat16* A0, int ld0, int K0, const __hip_bfloat16* A1,
                                           int ld1, const __hip_bfloat16* Wt, int ldW, int wn0, int cm0, int k0,
                                           char* smA, char* smB) {
    int tid = threadIdx.x, wid = tid >> 6, lane = tid & 63;
    int rseg = lane >> 3, slot = lane & 7;
    const __hip_bfloat16* Ab;
    int ldA, kloc;
    if (k0 < K0) {
        Ab = A0; ldA = ld0; kloc = k0;
    } else {
        Ab = A1; ldA = ld1; kloc = k0 - K0;
    }
#pragma unroll
    for (int i = 0; i < 2; ++i) {
        int seg = wid * 2 + i;
        int row = seg * 8 + rseg;
        int kk = kloc + ((slot ^ (row & 7)) << 3);
        gload_lds16(Ab + (size_t)(cm0 + row) * ldA + kk, smA + seg * 1024);
    }
#pragma unroll
    for (int i = 0; i < NFC; ++i) {
        int seg = wid * NFC + i;
        int row = seg * 8 + rseg;
        int kk = k0 + ((slot ^ (row & 7)) << 3);
        gload_lds16(Wt + (size_t)(wn0 + row) * ldW + kk, smB + seg * 1024);
    }
}

template <int NFC>
__device__ __forceinline__ void compute_tile(const char* smA, const char* smB, f32x4 (&acc)[2][NFC]) {
    int lane = threadIdx.x & 63, wid = threadIdx.x >> 6;
    int wr = wid >> 1, wc = wid & 1;
#pragma unroll
    for (int ks = 0; ks < 2; ++ks) {
        short8 af[2], bfr[NFC];
        int kslot = ks * 4 + (lane >> 4);
#pragma unroll
        for (int m = 0; m < 2; ++m) {
            int row = wr * 32 + m * 16 + (lane & 15);
            af[m] = *(const short8*)(smA + row * 128 + ((kslot ^ (row & 7)) << 4));
        }
#pragma unroll
        for (int n = 0; n < NFC; ++n) {
            int row = wc * (16 * NFC) + n * 16 + (lane & 15);
            bfr[n] = *(const short8*)(smB + row * 128 + ((kslot ^ (row & 7)) << 4));
        }
#pragma unroll
        for (int m = 0; m < 2; ++m)
#pragma unroll
            for (int n = 0; n < NFC; ++n) acc[m][n] = mfma16(af[m], bfr[n], acc[m][n]);
    }
}

template <int NFC>
__device__ __forceinline__ void gemm_tile_db(const __hip_bfloat16* A0, int ld0, int K0, const __hip_bfloat16* A1,
                                             int ld1, const __hip_bfloat16* Wt, int ldW, int wn0, float* C, int ldc,
                                             int cm0, int cn0, int nK, char* smem) {
    char* smA[2] = {smem, smem + 8192};
    char* smB[2] = {smem + 16384, smem + 16384 + NFC * 4096};
    f32x4 acc[2][NFC] = {};
    stage_tile<NFC>(A0, ld0, K0, A1, ld1, Wt, ldW, wn0, cm0, 0, smA[0], smB[0]);
    for (int kt = 0; kt < nK; ++kt) {
        if (kt + 1 < nK) {
            stage_tile<NFC>(A0, ld0, K0, A1, ld1, Wt, ldW, wn0, cm0, (kt + 1) * 64, smA[(kt + 1) & 1],
                            smB[(kt + 1) & 1]);
            if constexpr (NFC == 3) asm volatile("s_waitcnt vmcnt(5)" ::: "memory");
            else asm volatile("s_waitcnt vmcnt(4)" ::: "memory");
        } else {
            asm volatile("s_waitcnt vmcnt(0)" ::: "memory");
        }
        __builtin_amdgcn_s_barrier();
        compute_tile<NFC>(smA[kt & 1], smB[kt & 1], acc);
        __builtin_amdgcn_s_barrier();
    }
    int lane = threadIdx.x & 63, wid = threadIdx.x >> 6;
    int wr = wid >> 1, wc = wid & 1;
    int r0 = cm0 + wr * 32 + ((lane >> 4) << 2);
    int c0 = cn0 + wc * 16 * NFC + (lane & 15);
#pragma unroll
    for (int m = 0; m < 2; ++m)
#pragma unroll
        for (int n = 0; n < NFC; ++n)
#pragma unroll
            for (int i = 0; i < 4; ++i)
                C[(size_t)(r0 + m * 16 + i) * ldc + c0 + n * 16] = acc[m][n][i];
}

__global__ __launch_bounds__(256) void k_gemm_gru(const __hip_bfloat16* __restrict__ xbf,
                                                  const __hip_bfloat16* __restrict__ dbf,
                                                  const __hip_bfloat16* __restrict__ WgT,
                                                  float* __restrict__ gates) {
    __shared__ __align__(16) char smem[40960];
    int bm = blockIdx.x & 15, bn = blockIdx.x >> 4;
    gemm_tile_db<3>(xbf, 512, 512, dbf, 512, WgT, 1024, bn * 96, gates, G3N, bm * 64, bn * 96, 16, smem);
}

// ==== K2: fused LN/update + STAGED h-GEMMs + stats + outputs + next-step prior_in ====
__global__ __launch_bounds__(512) void k_step2(
    int t, const float* __restrict__ gates, float* __restrict__ deter, __hip_bfloat16* __restrict__ dbf,
    __hip_bfloat16* __restrict__ xbf, const __hip_bfloat16* __restrict__ obsbf, const int* __restrict__ isf,
    const float* __restrict__ action, const float* __restrict__ g_gru, const float* __restrict__ b_gru,
    const __hip_bfloat16* __restrict__ WpoT, const float* __restrict__ g_po, const float* __restrict__ b_po,
    const __hip_bfloat16* __restrict__ WpnT, const float* __restrict__ g_pn, const float* __restrict__ b_pn,
    const __hip_bfloat16* __restrict__ WpsT, const float* __restrict__ b_ps,
    const __hip_bfloat16* __restrict__ WptT, const float* __restrict__ b_pt,
    const __hip_bfloat16* __restrict__ WpiT, const float* __restrict__ g_pi, const float* __restrict__ b_pi,
    const float* __restrict__ dinit, const float* __restrict__ sinit, float* __restrict__ out) {
    __shared__ short dn_lds[16 * 512];   // 16KB
    __shared__ short stage[16 * 512];    // 16KB
    __shared__ __align__(16) short Bbuf[512 * 64];  // 64KB weight chunk
    __shared__ short a_lds[16 * 64];
    __shared__ float statsf[2 * 16 * 64];
    __shared__ float red[8 * 16 * 2];
    __shared__ float redc[16 * 2];
    __shared__ int flags[16];

    const int tid = threadIdx.x, wid = tid >> 6, lane = tid & 63, lr = lane & 15, lk = lane >> 4;
    const int grow = blockIdx.x * 16;
    const int prow = tid >> 5, pc = tid & 31;
    const int gr = grow + prow;
    const int j0 = pc * 16;

    // ---- phase 1: LN(gates) + GRU update ----
    {
        const float* gp = gates + (size_t)gr * G3N;
        float g0[16], g1[16], g2[16];
        float s = 0.f, q = 0.f;
#pragma unroll
        for (int e = 0; e < 16; e += 4) {
            f32x4 a = *(const f32x4*)(gp + j0 + e);
            f32x4 b = *(const f32x4*)(gp + 512 + j0 + e);
            f32x4 c = *(const f32x4*)(gp + 1024 + j0 + e);
#pragma unroll
            for (int u = 0; u < 4; ++u) {
                g0[e + u] = a[u];
                g1[e + u] = b[u];
                g2[e + u] = c[u];
                s += a[u] + b[u] + c[u];
                q += a[u] * a[u] + b[u] * b[u] + c[u] * c[u];
            }
        }
#pragma unroll
        for (int msk = 1; msk <= 16; msk <<= 1) {
            s += __shfl_xor(s, msk);
            q += __shfl_xor(q, msk);
        }
        float m = s * (1.f / 1536.f), iv = rsqrtf(q * (1.f / 1536.f) - m * m + LNEPS);
        float dn[16];
        float* dp = deter + (size_t)gr * 512 + j0;
#pragma unroll
        for (int e = 0; e < 16; e += 4) {
            f32x4 dv = *(const f32x4*)(dp + e);
#pragma unroll
            for (int u = 0; u < 4; ++u) {
                int col = j0 + e + u;
                float rv = sigmoidf_((g0[e + u] - m) * iv * g_gru[col] + b_gru[col]);
                float cv = (g1[e + u] - m) * iv * g_gru[512 + col] + b_gru[512 + col];
                float uv = sigmoidf_((g2[e + u] - m) * iv * g_gru[1024 + col] + b_gru[1024 + col] + UPDBIAS);
                dn[e + u] = uv * siluf_(rv * cv) + (1.f - uv) * dv[u];
            }
        }
        size_t ob = ((size_t)gr * TT + t) * OUTC + 160 + j0;
        short8 h0, h1;
#pragma unroll
        for (int e = 0; e < 16; e += 4) {
            *(f32x4*)(dp + e) = *(const f32x4*)&dn[e];
            *(f32x4*)(out + ob + e) = *(const f32x4*)&dn[e];
        }
#pragma unroll
        for (int u = 0; u < 8; ++u) {
            h0[u] = f2b(dn[u]);
            h1[u] = f2b(dn[8 + u]);
        }
        *(short8*)(dbf + (size_t)gr * 512 + j0) = h0;
        *(short8*)(dbf + (size_t)gr * 512 + j0 + 8) = h1;
        *(short8*)((char*)dn_lds + swz(prow, j0)) = h0;
        *(short8*)((char*)dn_lds + swz(prow, j0 + 8)) = h1;
    }
    __syncthreads();
    // ---- hq = silu(LN(cat(deter_n, obs_t) @ W_pn)), staged B ----
    {
        const __hip_bfloat16* op = obsbf + ((size_t)(grow + lr) * TT + t) * OBSN;
        dense512_staged<true>(dn_lds, WpnT, 576, op, g_pn, b_pn, stage, Bbuf, red, redc, wid, lr, lk);
    }
    __syncthreads();
    if (wid < 4) {  // qs = hq @ W_pt + b_pt
        f32x4 aq = {};
        int col = wid * 16 + lr;
#pragma unroll 2
        for (int ks = 0; ks < 16; ++ks) {
            short8 a = frag_ld(stage, lr, ks, lk);
            short8 b = *(const short8*)(WptT + (size_t)col * 512 + ks * 32 + lk * 8);
            aq = mfma16(a, b, aq);
        }
        float bias = b_pt[col];
#pragma unroll
        for (int i = 0; i < 4; ++i) statsf[(lk * 4 + i) * 64 + col] = aq[i] + bias;
    }
    __syncthreads();
    // ---- hp = silu(LN(deter_n @ W_po)), staged B ----
    dense512_staged<false>(dn_lds, WpoT, 512, nullptr, g_po, b_po, stage, Bbuf, red, redc, wid, lr, lk);
    __syncthreads();
    if (wid < 4) {  // ps = hp @ W_ps + b_ps
        f32x4 ap = {};
        int col = wid * 16 + lr;
#pragma unroll 2
        for (int ks = 0; ks < 16; ++ks) {
            short8 a = frag_ld(stage, lr, ks, lk);
            short8 b = *(const short8*)(WpsT + (size_t)col * 512 + ks * 32 + lk * 8);
            ap = mfma16(a, b, ap);
        }
        float bias = b_ps[col];
#pragma unroll
        for (int i = 0; i < 4; ++i) statsf[1024 + (lk * 4 + i) * 64 + col] = ap[i] + bias;
    }
    __syncthreads();
    // ---- P4: stats outputs + next-step inputs ----
    {
        size_t ob = ((size_t)gr * TT + t) * OUTC;
        if (pc < 32) {
            float qm = statsf[prow * 64 + pc];
            float pm = statsf[1024 + prow * 64 + pc];
            float qr = statsf[prow * 64 + 32 + pc];
            float pr = statsf[1024 + prow * 64 + 32 + pc];
            out[ob + pc] = qm;
            out[ob + 32 + pc] = softplusf_(qr) + MINSTD;
            out[ob + 64 + pc] = qm;
            out[ob + 96 + pc] = pm;
            out[ob + 128 + pc] = softplusf_(pr) + MINSTD;
            if (t + 1 < TT) {
                int f1 = isf[(size_t)gr * TT + t + 1] > 0;
                if (pc == 0) flags[prow] = f1;
                *(short*)((char*)a_lds + swz64(prow, pc)) = f2b(f1 ? sinit[pc] : qm);
                float av = (pc < ACTN) ? (f1 ? 0.f : action[((size_t)gr * TT + t + 1) * ACTN + pc]) : 0.f;
                *(short*)((char*)a_lds + swz64(prow, 32 + pc)) = f2b(av);
            }
        }
    }
    if (t + 1 >= TT) return;
    __syncthreads();
    if (flags[prow]) {  // deter reset for is_first rows
        short8 h0, h1;
#pragma unroll
        for (int e = 0; e < 16; e += 4)
            *(f32x4*)(deter + (size_t)gr * 512 + j0 + e) = *(const f32x4*)(dinit + j0 + e);
#pragma unroll
        for (int u = 0; u < 8; ++u) {
            h0[u] = f2b(dinit[j0 + u]);
            h1[u] = f2b(dinit[j0 + 8 + u]);
        }
        *(short8*)(dbf + (size_t)gr * 512 + j0) = h0;
        *(short8*)(dbf + (size_t)gr * 512 + j0 + 8) = h1;
    }
    __syncthreads();
    prior_gemm(a_lds, WpiT, g_pi, b_pi, xbf, grow, red, redc, wid, lr, lk);
}

// ==== t=0 state + first prior_in ====
__global__ __launch_bounds__(512) void k_prior0(const int* __restrict__ isf, const float* __restrict__ action,
                                                const float* __restrict__ dinit, const float* __restrict__ sinit,
                                                const __hip_bfloat16* __restrict__ WpiT,
                                                const float* __restrict__ g_pi, const float* __restrict__ b_pi,
                                                float* __restrict__ deter, __hip_bfloat16* __restrict__ dbf,
                                                __hip_bfloat16* __restrict__ xbf) {
    __shared__ short a_lds[16 * 64];
    __shared__ float red[8 * 16 * 2];
    __shared__ float redc[16 * 2];
    const int tid = threadIdx.x, wid = tid >> 6, lane = tid & 63, lr = lane & 15, lk = lane >> 4;
    const int grow = blockIdx.x * 16;
    const int prow = tid >> 5, pc = tid & 31;
    const int gr = grow + prow;
    const int j0 = pc * 16;
    {
        int f0 = isf[(size_t)gr * TT] > 0;
        if (pc < 32) {
            *(short*)((char*)a_lds + swz64(prow, pc)) = f2b(sinit[pc]);
            float av = (pc < ACTN) ? (f0 ? 0.f : action[(size_t)gr * TT * ACTN + pc]) : 0.f;
            *(short*)((char*)a_lds + swz64(prow, 32 + pc)) = f2b(av);
        }
        short8 h0, h1;
#pragma unroll
        for (int e = 0; e < 16; e += 4)
            *(f32x4*)(deter + (size_t)gr * 512 + j0 + e) = *(const f32x4*)(dinit + j0 + e);
#pragma unroll
        for (int u = 0; u < 8; ++u) {
            h0[u] = f2b(dinit[j0 + u]);
            h1[u] = f2b(dinit[j0 + 8 + u]);
        }
        *(short8*)(dbf + (size_t)gr * 512 + j0) = h0;
        *(short8*)(dbf + (size_t)gr * 512 + j0 + 8) = h1;
    }
    __syncthreads();
    prior_gemm(a_lds, WpiT, g_pi, b_pi, xbf, grow, red, redc, wid, lr, lk);
}

// ---- block-wide reduction (k_init only) ----
template <int NV>
__device__ __forceinline__ void breduce(float* v, float* red, int nwaves) {
    __syncthreads();
#pragma unroll
    for (int off = 32; off > 0; off >>= 1)
#pragma unroll
        for (int q = 0; q < NV; ++q) v[q] += __shfl_down(v[q], off);
    int lane = threadIdx.x & 63, w = threadIdx.x >> 6;
    if (lane == 0)
        for (int q = 0; q < NV; ++q) red[w * NV + q] = v[q];
    __syncthreads();
    if ((int)threadIdx.x < NV) {
        float s = 0.f;
        for (int ww = 0; ww < nwaves; ++ww) s += red[ww * NV + threadIdx.x];
        red[nwaves * NV + threadIdx.x] = s;
    }
    __syncthreads();
#pragma unroll
    for (int q = 0; q < NV; ++q) v[q] = red[nwaves * NV + q];
}

__global__ __launch_bounds__(512) void k_init(const float* __restrict__ init_deter, const float* __restrict__ W_po,
                                              const float* __restrict__ g_po, const float* __restrict__ b_po,
                                              const float* __restrict__ W_ps, const float* __restrict__ b_ps,
                                              float* __restrict__ dinit, float* __restrict__ sinit) {
    __shared__ float d_s[512], h_s[512], red[40];
    int tid = threadIdx.x;
    float dv = tanhf(init_deter[tid]);
    d_s[tid] = dv;
    dinit[tid] = dv;
    __syncthreads();
    float acc = 0.f;
    for (int k = 0; k < 512; ++k) acc += d_s[k] * W_po[k * 512 + tid];
    float v[2] = {acc, acc * acc};
    breduce<2>(v, red, 8);
    float m = v[0] / 512.f, va = v[1] / 512.f - m * m, iv = rsqrtf(va + LNEPS);
    h_s[tid] = siluf_((acc - m) * iv * g_po[tid] + b_po[tid]);
    __syncthreads();
    if (tid < 32) {
        float s = b_ps[tid];
        for (int k = 0; k < 512; ++k) s += h_s[k] * W_ps[k * 64 + tid];
        sinit[tid] = s;
    }
}

__global__ __launch_bounds__(256) void k_transpose_bf(const float* __restrict__ src,
                                                      __hip_bfloat16* __restrict__ dst, int K, int N) {
    __shared__ float tle[32][33];
    int nTK = K >> 5;
    int k0 = (blockIdx.x % nTK) * 32;
    int n0 = (blockIdx.x / nTK) * 32;
    int tx = threadIdx.x & 31, ty = threadIdx.x >> 5;
#pragma unroll
    for (int i = 0; i < 4; ++i) tle[ty + i * 8][tx] = src[(size_t)(k0 + ty + i * 8) * N + n0 + tx];
    __syncthreads();
#pragma unroll
    for (int i = 0; i < 4; ++i)
        dst[(size_t)(n0 + ty + i * 8) * K + k0 + tx] = __float2bfloat16(tle[tx][ty + i * 8]);
}

__global__ __launch_bounds__(256) void k_wpi_pad(const float* __restrict__ W_pi,
                                                 __hip_bfloat16* __restrict__ WpiT) {
    int idx = blockIdx.x * 256 + threadIdx.x;
    if (idx >= 512 * 64) return;
    int n = idx >> 6, k = idx & 63;
    WpiT[idx] = __float2bfloat16(k < CATPI ? W_pi[k * 512 + n] : 0.f);
}

__global__ __launch_bounds__(256) void k_cvt_bf(const float* __restrict__ src, __hip_bfloat16* __restrict__ dst,
                                                int n) {
    for (int i = blockIdx.x * 256 + threadIdx.x; i < n; i += gridDim.x * 256) dst[i] = __float2bfloat16(src[i]);
}

extern "C" void kernel_launch(void* const* d_in, const int* in_sizes, int n_in, void* d_out, int out_size, void* d_ws,
                              size_t ws_size, hipStream_t stream) {
    const float* obs = (const float*)d_in[0];
    const float* action = (const float*)d_in[1];
    const int* is_first = (const int*)d_in[2];
    const float* W_pi = (const float*)d_in[3];
    const float* g_pi = (const float*)d_in[4];
    const float* b_pi = (const float*)d_in[5];
    const float* W_gru = (const float*)d_in[6];
    const float* g_gru = (const float*)d_in[7];
    const float* b_gru = (const float*)d_in[8];
    const float* W_po = (const float*)d_in[9];
    const float* g_po = (const float*)d_in[10];
    const float* b_po = (const float*)d_in[11];
    const float* W_ps = (const float*)d_in[12];
    const float* b_ps = (const float*)d_in[13];
    const float* W_pn = (const float*)d_in[14];
    const float* g_pn = (const float*)d_in[15];
    const float* b_pn = (const float*)d_in[16];
    const float* W_pt = (const float*)d_in[17];
    const float* b_pt = (const float*)d_in[18];
    const float* init_deter = (const float*)d_in[19];
    float* out = (float*)d_out;

    char* p = (char*)d_ws;
    auto alloc = [&](size_t bytes) {
        char* r = p;
        p += (bytes + 255) & ~(size_t)255;
        return r;
    };
    float* gates = (float*)alloc((size_t)BB * G3N * 4);
    float* deter = (float*)alloc((size_t)BB * 512 * 4);
    float* dinit = (float*)alloc(512 * 4);
    float* sinit = (float*)alloc(64 * 4);
    __hip_bfloat16* xbf = (__hip_bfloat16*)alloc((size_t)BB * 512 * 2);
    __hip_bfloat16* dbf = (__hip_bfloat16*)alloc((size_t)BB * 512 * 2);
    __hip_bfloat16* obsbf = (__hip_bfloat16*)alloc((size_t)BB * TT * OBSN * 2);
    __hip_bfloat16* WgT = (__hip_bfloat16*)alloc((size_t)G3N * 1024 * 2);
    __hip_bfloat16* WpoT = (__hip_bfloat16*)alloc((size_t)512 * 512 * 2);
    __hip_bfloat16* WpnT = (__hip_bfloat16*)alloc((size_t)512 * 576 * 2);
    __hip_bfloat16* WpsT = (__hip_bfloat16*)alloc((size_t)64 * 512 * 2);
    __hip_bfloat16* WptT = (__hip_bfloat16*)alloc((size_t)64 * 512 * 2);
    __hip_bfloat16* WpiT = (__hip_bfloat16*)alloc((size_t)512 * 64 * 2);

    k_transpose_bf<<<(1024 / 32) * (G3N / 32), 256, 0, stream>>>(W_gru, WgT, 1024, G3N);
    k_transpose_bf<<<(512 / 32) * (512 / 32), 256, 0, stream>>>(W_po, WpoT, 512, 512);
    k_transpose_bf<<<(576 / 32) * (512 / 32), 256, 0, stream>>>(W_pn, WpnT, 576, 512);
    k_transpose_bf<<<(512 / 32) * (64 / 32), 256, 0, stream>>>(W_ps, WpsT, 512, 64);
    k_transpose_bf<<<(512 / 32) * (64 / 32), 256, 0, stream>>>(W_pt, WptT, 512, 64);
    k_wpi_pad<<<128, 256, 0, stream>>>(W_pi, WpiT);
    k_cvt_bf<<<2048, 256, 0, stream>>>(obs, obsbf, BB * TT * OBSN);
    k_init<<<1, 512, 0, stream>>>(init_deter, W_po, g_po, b_po, W_ps, b_ps, dinit, sinit);
    k_prior0<<<64, 512, 0, stream>>>(is_first, action, dinit, sinit, WpiT, g_pi, b_pi, deter, dbf, xbf);

    for (int t = 0; t < TT; ++t) {
        k_gemm_gru<<<256, 256, 0, stream>>>(xbf, dbf, WgT, gates);
        k_step2<<<64, 512, 0, stream>>>(t, gates, deter, dbf, xbf, obsbf, is_first, action, g_gru, b_gru, WpoT,
                                        g_po, b_po, WpnT, g_pn, b_pn, WpsT, b_ps, WptT, b_pt, WpiT, g_pi, b_pi,
                                        dinit, sinit, out);
    }
}

// Round 9
// 2973.689 us; speedup vs baseline: 3.3695x; 1.4154x over previous
//
#include <hip/hip_runtime.h>
#include <hip/hip_bf16.h>
#include <math.h>

#define BB 1024
#define TT 64
#define OBSN 64
#define ACTN 8
#define STOCHN 32
#define DETERN 512
#define HIDN 512
#define G3N 1536
#define CATPI 40
#define OUTC 672
#define LNEPS 1e-3f
#define MINSTD 0.1f
#define UPDBIAS -1.0f

typedef __attribute__((ext_vector_type(8))) short short8;
typedef __attribute__((ext_vector_type(4))) float f32x4;

__device__ __forceinline__ float sigmoidf_(float x) { return 1.f / (1.f + expf(-x)); }
__device__ __forceinline__ float siluf_(float x) { return x / (1.f + expf(-x)); }
__device__ __forceinline__ float softplusf_(float x) { return (x > 20.f) ? x : log1pf(expf(x)); }

__device__ __forceinline__ float b2f(short u) {
    unsigned x = ((unsigned)(unsigned short)u) << 16;
    return __builtin_bit_cast(float, x);
}
__device__ __forceinline__ short f2b(float f) {
    __hip_bfloat16 h = __float2bfloat16(f);
    return __builtin_bit_cast(short, h);
}

__device__ __forceinline__ f32x4 mfma16(short8 a, short8 b, f32x4 c) {
    return __builtin_amdgcn_mfma_f32_16x16x32_bf16(a, b, c, 0, 0, 0);
}

__device__ __forceinline__ void gload_lds16(const void* g, void* l) {
    __builtin_amdgcn_global_load_lds((const __attribute__((address_space(1))) void*)g,
                                     (__attribute__((address_space(3))) void*)l, 16, 0, 0);
}

__device__ __forceinline__ void wred2(float& a, float& b) {
#pragma unroll
    for (int off = 32; off; off >>= 1) {
        a += __shfl_xor(a, off);
        b += __shfl_xor(b, off);
    }
}

// ---- swizzled bf16 [R][512] LDS tile: row stride 1024 B, 16B slots XOR'd by row&7 ----
__device__ __forceinline__ short8 frag_ld(const short* base, int row, int ks, int lk) {
    int slot = (ks * 4 + lk) ^ (row & 7);
    return *(const short8*)((const char*)base + row * 1024 + (slot << 4));
}
__device__ __forceinline__ int swz(int row, int col) {
    return row * 1024 + ((((col >> 3) ^ (row & 7)) << 4) | ((col & 7) << 1));
}
// ---- swizzled bf16 rows of 64 cols (128 B stride) for B chunks [512 n][64 K] ----
__device__ __forceinline__ short8 frag_ld64(const short* base, int row, int ks, int lk) {
    int slot = ((ks * 4 + lk) ^ (row & 7)) & 7;
    return *(const short8*)((const char*)base + row * 128 + (slot << 4));
}

// ---- cross-wave LN combine (8 waves, 16 rows) ----
__device__ __forceinline__ void ln_combine(float s[4], float q[4], float invn, float* red, float* redc, int wid,
                                           int lr, int lk, float m[4], float iv[4]) {
#pragma unroll
    for (int msk = 1; msk <= 8; msk <<= 1)
#pragma unroll
        for (int i = 0; i < 4; ++i) {
            s[i] += __shfl_xor(s[i], msk);
            q[i] += __shfl_xor(q[i], msk);
        }
    if (lr == 0)
#pragma unroll
        for (int i = 0; i < 4; ++i) {
            red[(wid * 16 + lk * 4 + i) * 2 + 0] = s[i];
            red[(wid * 16 + lk * 4 + i) * 2 + 1] = q[i];
        }
    __syncthreads();
    int tid = threadIdx.x;
    if (tid < 32) {
        int row = tid >> 1, v = tid & 1;
        float a = 0.f;
#pragma unroll
        for (int w = 0; w < 8; ++w) a += red[(w * 16 + row) * 2 + v];
        redc[row * 2 + v] = a;
    }
    __syncthreads();
#pragma unroll
    for (int i = 0; i < 4; ++i) {
        int row = lk * 4 + i;
        float mm = redc[row * 2] * invn;
        float vv = redc[row * 2 + 1] * invn - mm * mm;
        m[i] = mm;
        iv[i] = rsqrtf(vv + LNEPS);
    }
}

// ---- STAGED dense 16x512 @ Wt[512][512]^T -> LN -> silu -> bf16 swizzled dst (512 thr) ----
__device__ __forceinline__ void dense512_staged(const short* A_lds, const __hip_bfloat16* Wt, const float* gg,
                                                const float* bb, short* dst, short* Bbuf, float* red, float* redc,
                                                int wid, int lr, int lk) {
    f32x4 acc[4] = {};
    const int c0 = wid * 64 + lr;
    const int lane = threadIdx.x & 63;
    const int rseg = lane >> 3, slot = lane & 7;
    for (int ck = 0; ck < 8; ++ck) {
#pragma unroll
        for (int i = 0; i < 8; ++i) {
            int seg = wid * 8 + i;
            int row = seg * 8 + rseg;
            int kk = ck * 64 + ((slot ^ (row & 7)) << 3);
            gload_lds16(Wt + (size_t)row * 512 + kk, (char*)Bbuf + seg * 1024);
        }
        asm volatile("s_waitcnt vmcnt(0)" ::: "memory");
        __builtin_amdgcn_s_barrier();
#pragma unroll
        for (int ks = 0; ks < 2; ++ks) {
            short8 a = frag_ld(A_lds, lr, ck * 2 + ks, lk);
#pragma unroll
            for (int f = 0; f < 4; ++f) acc[f] = mfma16(a, frag_ld64(Bbuf, c0 + f * 16, ks, lk), acc[f]);
        }
        __builtin_amdgcn_s_barrier();
    }
    float s[4] = {}, q[4] = {};
#pragma unroll
    for (int f = 0; f < 4; ++f)
#pragma unroll
        for (int i = 0; i < 4; ++i) {
            float v = acc[f][i];
            s[i] += v;
            q[i] += v * v;
        }
    float m[4], iv[4];
    ln_combine(s, q, 1.f / 512.f, red, redc, wid, lr, lk, m, iv);
#pragma unroll
    for (int f = 0; f < 4; ++f) {
        int col = c0 + f * 16;
        float g = gg[col], b = bb[col];
#pragma unroll
        for (int i = 0; i < 4; ++i) {
            float v = siluf_((acc[f][i] - m[i]) * iv[i] * g + b);
            *(short*)((char*)dst + swz(lk * 4 + i, col)) = f2b(v);
        }
    }
}

// ==== K1: GRU GEMM, 256 blocks of 64x96 (validated double-buffered core) ====
template <int NFC>
__device__ __forceinline__ void stage_tile(const __hip_bfloat16* A0, int ld0, int K0, const __hip_bfloat16* A1,
                                           int ld1, const __hip_bfloat16* Wt, int ldW, int wn0, int cm0, int k0,
                                           char* smA, char* smB) {
    int tid = threadIdx.x, wid = tid >> 6, lane = tid & 63;
    int rseg = lane >> 3, slot = lane & 7;
    const __hip_bfloat16* Ab;
    int ldA, kloc;
    if (k0 < K0) {
        Ab = A0; ldA = ld0; kloc = k0;
    } else {
        Ab = A1; ldA = ld1; kloc = k0 - K0;
    }
#pragma unroll
    for (int i = 0; i < 2; ++i) {
        int seg = wid * 2 + i;
        int row = seg * 8 + rseg;
        int kk = kloc + ((slot ^ (row & 7)) << 3);
        gload_lds16(Ab + (size_t)(cm0 + row) * ldA + kk, smA + seg * 1024);
    }
#pragma unroll
    for (int i = 0; i < NFC; ++i) {
        int seg = wid * NFC + i;
        int row = seg * 8 + rseg;
        int kk = k0 + ((slot ^ (row & 7)) << 3);
        gload_lds16(Wt + (size_t)(wn0 + row) * ldW + kk, smB + seg * 1024);
    }
}

template <int NFC>
__device__ __forceinline__ void compute_tile(const char* smA, const char* smB, f32x4 (&acc)[2][NFC]) {
    int lane = threadIdx.x & 63, wid = threadIdx.x >> 6;
    int wr = wid >> 1, wc = wid & 1;
#pragma unroll
    for (int ks = 0; ks < 2; ++ks) {
        short8 af[2], bfr[NFC];
        int kslot = ks * 4 + (lane >> 4);
#pragma unroll
        for (int m = 0; m < 2; ++m) {
            int row = wr * 32 + m * 16 + (lane & 15);
            af[m] = *(const short8*)(smA + row * 128 + ((kslot ^ (row & 7)) << 4));
        }
#pragma unroll
        for (int n = 0; n < NFC; ++n) {
            int row = wc * (16 * NFC) + n * 16 + (lane & 15);
            bfr[n] = *(const short8*)(smB + row * 128 + ((kslot ^ (row & 7)) << 4));
        }
#pragma unroll
        for (int m = 0; m < 2; ++m)
#pragma unroll
            for (int n = 0; n < NFC; ++n) acc[m][n] = mfma16(af[m], bfr[n], acc[m][n]);
    }
}

template <int NFC>
__device__ __forceinline__ void gemm_tile_db(const __hip_bfloat16* A0, int ld0, int K0, const __hip_bfloat16* A1,
                                             int ld1, const __hip_bfloat16* Wt, int ldW, int wn0, float* C, int ldc,
                                             int cm0, int cn0, int nK, char* smem) {
    char* smA[2] = {smem, smem + 8192};
    char* smB[2] = {smem + 16384, smem + 16384 + NFC * 4096};
    f32x4 acc[2][NFC] = {};
    stage_tile<NFC>(A0, ld0, K0, A1, ld1, Wt, ldW, wn0, cm0, 0, smA[0], smB[0]);
    for (int kt = 0; kt < nK; ++kt) {
        if (kt + 1 < nK) {
            stage_tile<NFC>(A0, ld0, K0, A1, ld1, Wt, ldW, wn0, cm0, (kt + 1) * 64, smA[(kt + 1) & 1],
                            smB[(kt + 1) & 1]);
            if constexpr (NFC == 3) asm volatile("s_waitcnt vmcnt(5)" ::: "memory");
            else asm volatile("s_waitcnt vmcnt(4)" ::: "memory");
        } else {
            asm volatile("s_waitcnt vmcnt(0)" ::: "memory");
        }
        __builtin_amdgcn_s_barrier();
        compute_tile<NFC>(smA[kt & 1], smB[kt & 1], acc);
        __builtin_amdgcn_s_barrier();
    }
    int lane = threadIdx.x & 63, wid = threadIdx.x >> 6;
    int wr = wid >> 1, wc = wid & 1;
    int r0 = cm0 + wr * 32 + ((lane >> 4) << 2);
    int c0 = cn0 + wc * 16 * NFC + (lane & 15);
#pragma unroll
    for (int m = 0; m < 2; ++m)
#pragma unroll
        for (int n = 0; n < NFC; ++n)
#pragma unroll
            for (int i = 0; i < 4; ++i)
                C[(size_t)(r0 + m * 16 + i) * ldc + c0 + n * 16] = acc[m][n][i];
}

__global__ __launch_bounds__(256) void k_gemm_gru(const __hip_bfloat16* __restrict__ xbf,
                                                  const __hip_bfloat16* __restrict__ dbf,
                                                  const __hip_bfloat16* __restrict__ WgT,
                                                  float* __restrict__ gates) {
    __shared__ __align__(16) char smem[40960];
    int bm = blockIdx.x & 15, bn = blockIdx.x >> 4;
    gemm_tile_db<3>(xbf, 512, 512, dbf, 512, WgT, 1024, bn * 96, gates, G3N, bm * 64, bn * 96, 16, smem);
}

// ==== K2: LN(gates) + GRU update -> deter, dbf, out deter-cols. 128 blocks x 256 thr (8 rows) ====
__global__ __launch_bounds__(256) void k_update(int t, const float* __restrict__ gates,
                                                const float* __restrict__ g_gru, const float* __restrict__ b_gru,
                                                float* __restrict__ deter, __hip_bfloat16* __restrict__ dbf,
                                                float* __restrict__ out) {
    const int tid = threadIdx.x;
    const int prow = tid >> 5, pc = tid & 31;
    const int gr = blockIdx.x * 8 + prow;
    const int j0 = pc * 16;
    const float* gp = gates + (size_t)gr * G3N;
    float g0[16], g1[16], g2[16];
    float s = 0.f, q = 0.f;
#pragma unroll
    for (int e = 0; e < 16; e += 4) {
        f32x4 a = *(const f32x4*)(gp + j0 + e);
        f32x4 b = *(const f32x4*)(gp + 512 + j0 + e);
        f32x4 c = *(const f32x4*)(gp + 1024 + j0 + e);
#pragma unroll
        for (int u = 0; u < 4; ++u) {
            g0[e + u] = a[u];
            g1[e + u] = b[u];
            g2[e + u] = c[u];
            s += a[u] + b[u] + c[u];
            q += a[u] * a[u] + b[u] * b[u] + c[u] * c[u];
        }
    }
#pragma unroll
    for (int msk = 1; msk <= 16; msk <<= 1) {
        s += __shfl_xor(s, msk);
        q += __shfl_xor(q, msk);
    }
    float m = s * (1.f / 1536.f), iv = rsqrtf(q * (1.f / 1536.f) - m * m + LNEPS);
    float dn[16];
    float* dp = deter + (size_t)gr * 512 + j0;
#pragma unroll
    for (int e = 0; e < 16; e += 4) {
        f32x4 dv = *(const f32x4*)(dp + e);
#pragma unroll
        for (int u = 0; u < 4; ++u) {
            int col = j0 + e + u;
            float rv = sigmoidf_((g0[e + u] - m) * iv * g_gru[col] + b_gru[col]);
            float cv = (g1[e + u] - m) * iv * g_gru[512 + col] + b_gru[512 + col];
            float uv = sigmoidf_((g2[e + u] - m) * iv * g_gru[1024 + col] + b_gru[1024 + col] + UPDBIAS);
            dn[e + u] = uv * siluf_(rv * cv) + (1.f - uv) * dv[u];
        }
    }
    size_t ob = ((size_t)gr * TT + t) * OUTC + 160 + j0;
    short8 h0, h1;
#pragma unroll
    for (int e = 0; e < 16; e += 4) {
        *(f32x4*)(dp + e) = *(const f32x4*)&dn[e];
        *(f32x4*)(out + ob + e) = *(const f32x4*)&dn[e];
    }
#pragma unroll
    for (int u = 0; u < 8; ++u) {
        h0[u] = f2b(dn[u]);
        h1[u] = f2b(dn[8 + u]);
    }
    *(short8*)(dbf + (size_t)gr * 512 + j0) = h0;
    *(short8*)(dbf + (size_t)gr * 512 + j0 + 8) = h1;
}

// ==== K3: hq_raw = cat(deter_n, obs_t) @ W_pn. 128 blocks of 64x64, K=576 ====
__global__ __launch_bounds__(256) void k_gemm_hq(int t, const __hip_bfloat16* __restrict__ dbf,
                                                 const __hip_bfloat16* __restrict__ obsbf,
                                                 const __hip_bfloat16* __restrict__ WpnT,
                                                 float* __restrict__ hq_raw) {
    __shared__ __align__(16) char smem[32768];
    int bm = blockIdx.x & 15, bn = blockIdx.x >> 4;  // bn 0..7
    gemm_tile_db<2>(dbf, 512, 512, obsbf + (size_t)t * OBSN, TT * OBSN, WpnT, 576, bn * 64, hq_raw, 512, bm * 64,
                    bn * 64, 9, smem);
}

// ==== K4: LN(hq)+silu, qs stats, outputs, reset, next prior_in. 256 blocks x 256 thr (4 rows) ====
__global__ __launch_bounds__(256) void k_finish(int t, const float* __restrict__ hq_raw,
                                                const float* __restrict__ g_pn, const float* __restrict__ b_pn,
                                                const __hip_bfloat16* __restrict__ WptT,
                                                const float* __restrict__ b_pt, const int* __restrict__ isf,
                                                const float* __restrict__ action, const float* __restrict__ dinit,
                                                const float* __restrict__ sinit, float* __restrict__ deter,
                                                __hip_bfloat16* __restrict__ dbf,
                                                const __hip_bfloat16* __restrict__ Wpibf,
                                                const float* __restrict__ g_pi, const float* __restrict__ b_pi,
                                                __hip_bfloat16* __restrict__ xbf, float* __restrict__ out) {
    __shared__ float hql[4][512];
    __shared__ float a_ls[4][40];
    const int wid = threadIdx.x >> 6, l = threadIdx.x & 63;
    const int gr = blockIdx.x * 4 + wid;
    const int j0 = l * 8;
    const float* hr = hq_raw + (size_t)gr * 512;
    float h[8];
    *(f32x4*)&h[0] = *(const f32x4*)(hr + j0);
    *(f32x4*)&h[4] = *(const f32x4*)(hr + j0 + 4);
    float s = 0.f, q = 0.f;
#pragma unroll
    for (int e = 0; e < 8; ++e) {
        s += h[e];
        q += h[e] * h[e];
    }
    wred2(s, q);
    float m = s * (1.f / 512.f), iv = rsqrtf(q * (1.f / 512.f) - m * m + LNEPS);
#pragma unroll
    for (int e = 0; e < 8; ++e) h[e] = siluf_((h[e] - m) * iv * g_pn[j0 + e] + b_pn[j0 + e]);
    *(f32x4*)&hql[wid][j0] = *(const f32x4*)&h[0];
    *(f32x4*)&hql[wid][j0 + 4] = *(const f32x4*)&h[4];
    __syncthreads();
    // qs stats: lane l = col (64 cols)
    float acc = b_pt[l];
    const __hip_bfloat16* wr = WptT + (size_t)l * 512;
    const float* hq = hql[wid];
#pragma unroll 4
    for (int k0 = 0; k0 < 512; k0 += 8) {
        short8 w = *(const short8*)(wr + k0);
        f32x4 a0 = *(const f32x4*)(hq + k0);
        f32x4 a1 = *(const f32x4*)(hq + k0 + 4);
#pragma unroll
        for (int e = 0; e < 4; ++e) {
            acc += b2f(w[e]) * a0[e];
            acc += b2f(w[4 + e]) * a1[e];
        }
    }
    size_t ob = ((size_t)gr * TT + t) * OUTC;
    if (l < 32) {
        out[ob + l] = acc;
        out[ob + 64 + l] = acc;
    } else {
        out[ob + 32 + (l - 32)] = softplusf_(acc) + MINSTD;
    }
    if (t + 1 >= TT) return;
    int f1 = isf[(size_t)gr * TT + t + 1] > 0;
    if (l < 32)
        a_ls[wid][l] = f1 ? sinit[l] : acc;
    else if (l < 40)
        a_ls[wid][l] = f1 ? 0.f : action[((size_t)gr * TT + t + 1) * ACTN + (l - 32)];
    if (f1) {
        f32x4 d0 = *(const f32x4*)(dinit + j0);
        f32x4 d1 = *(const f32x4*)(dinit + j0 + 4);
        *(f32x4*)(deter + (size_t)gr * 512 + j0) = d0;
        *(f32x4*)(deter + (size_t)gr * 512 + j0 + 4) = d1;
        short8 db;
#pragma unroll
        for (int e = 0; e < 4; ++e) {
            db[e] = f2b(d0[e]);
            db[4 + e] = f2b(d1[e]);
        }
        *(short8*)(dbf + (size_t)gr * 512 + j0) = db;
    }
    __syncthreads();
    // prior_in: x = silu(LN(a @ W_pi)) -> xbf
    float o[8] = {};
    const float* a_s = a_ls[wid];
    for (int k = 0; k < CATPI; ++k) {
        float a = a_s[k];
        short8 w = *(const short8*)(Wpibf + k * 512 + j0);
#pragma unroll
        for (int e = 0; e < 8; ++e) o[e] += a * b2f(w[e]);
    }
    float s2 = 0.f, q2 = 0.f;
#pragma unroll
    for (int e = 0; e < 8; ++e) {
        s2 += o[e];
        q2 += o[e] * o[e];
    }
    wred2(s2, q2);
    float m2 = s2 * (1.f / 512.f), iv2 = rsqrtf(q2 * (1.f / 512.f) - m2 * m2 + LNEPS);
    short8 xo;
#pragma unroll
    for (int e = 0; e < 8; ++e) xo[e] = f2b(siluf_((o[e] - m2) * iv2 * g_pi[j0 + e] + b_pi[j0 + e]));
    *(short8*)(xbf + (size_t)gr * 512 + j0) = xo;
}

// ==== deferred: p_mean/p_std for all B*T rows. 4096 blocks x 512 thr, M=16 ====
__global__ __launch_bounds__(512) void k_post_p(const float* __restrict__ outr,
                                                const __hip_bfloat16* __restrict__ WpoT,
                                                const float* __restrict__ g_po, const float* __restrict__ b_po,
                                                const __hip_bfloat16* __restrict__ WpsT,
                                                const float* __restrict__ b_ps, float* __restrict__ out) {
    __shared__ short A_lds[16 * 512];
    __shared__ short hp_lds[16 * 512];
    __shared__ __align__(16) short Bbuf[512 * 64];
    __shared__ float red[8 * 16 * 2];
    __shared__ float redc[16 * 2];
    const int tid = threadIdx.x, wid = tid >> 6, lane = tid & 63, lr = lane & 15, lk = lane >> 4;
    const int base = blockIdx.x * 16;
    // stage A: 16 rows x 512K of deter_n read from out cols 160.., fp32->bf16, swizzled
#pragma unroll
    for (int qq = 0; qq < 2; ++qq) {
        int sI = qq * 512 + tid;
        int row = sI >> 6, slot = sI & 63;
        int k = (slot ^ (row & 7)) << 3;
        const float* src = outr + ((size_t)(base + row) * OUTC + 160 + k);
        f32x4 a = *(const f32x4*)src;
        f32x4 b = *(const f32x4*)(src + 4);
        short8 v;
#pragma unroll
        for (int e = 0; e < 4; ++e) {
            v[e] = f2b(a[e]);
            v[4 + e] = f2b(b[e]);
        }
        *(short8*)((char*)A_lds + sI * 16) = v;
    }
    __syncthreads();
    // hp = silu(LN(A @ W_po))
    dense512_staged(A_lds, WpoT, g_po, b_po, hp_lds, Bbuf, red, redc, wid, lr, lk);
    __syncthreads();
    // stage WpsT [64][512] into Bbuf (1024B rows, swz)
#pragma unroll
    for (int qq = 0; qq < 8; ++qq) {
        int sI = qq * 512 + tid;
        int row = sI >> 6, slot = sI & 63;
        int k = (slot ^ (row & 7)) << 3;
        gload_lds16(WpsT + (size_t)row * 512 + k, (char*)Bbuf + (qq * 512 + wid * 64) * 16);
    }
    asm volatile("s_waitcnt vmcnt(0)" ::: "memory");
    __builtin_amdgcn_s_barrier();
    if (wid < 4) {
        f32x4 ap = {};
        int col = wid * 16 + lr;
#pragma unroll 2
        for (int ks = 0; ks < 16; ++ks) {
            short8 a = frag_ld(hp_lds, lr, ks, lk);
            short8 b = frag_ld(Bbuf, col, ks, lk);
            ap = mfma16(a, b, ap);
        }
        float bias = b_ps[col];
#pragma unroll
        for (int i = 0; i < 4; ++i) {
            int gidx = base + lk * 4 + i;
            float v = ap[i] + bias;
            if (col < 32)
                out[(size_t)gidx * OUTC + 96 + col] = v;
            else
                out[(size_t)gidx * OUTC + 128 + (col - 32)] = softplusf_(v) + MINSTD;
        }
    }
}

// ==== t=0 state + first prior_in (256 blocks x 256 thr, 4 rows) ====
__global__ __launch_bounds__(256) void k_prior0(const int* __restrict__ isf, const float* __restrict__ action,
                                                const float* __restrict__ dinit, const float* __restrict__ sinit,
                                                const __hip_bfloat16* __restrict__ Wpibf,
                                                const float* __restrict__ g_pi, const float* __restrict__ b_pi,
                                                float* __restrict__ deter, __hip_bfloat16* __restrict__ dbf,
                                                __hip_bfloat16* __restrict__ xbf) {
    __shared__ float a_ls[4][40];
    const int wid = threadIdx.x >> 6, l = threadIdx.x & 63;
    const int gr = blockIdx.x * 4 + wid;
    const int j0 = l * 8;
    int f0 = isf[(size_t)gr * TT] > 0;
    if (l < 32)
        a_ls[wid][l] = sinit[l];
    else if (l < 40)
        a_ls[wid][l] = f0 ? 0.f : action[(size_t)gr * TT * ACTN + (l - 32)];
    f32x4 d0 = *(const f32x4*)(dinit + j0);
    f32x4 d1 = *(const f32x4*)(dinit + j0 + 4);
    *(f32x4*)(deter + (size_t)gr * 512 + j0) = d0;
    *(f32x4*)(deter + (size_t)gr * 512 + j0 + 4) = d1;
    short8 db;
#pragma unroll
    for (int e = 0; e < 4; ++e) {
        db[e] = f2b(d0[e]);
        db[4 + e] = f2b(d1[e]);
    }
    *(short8*)(dbf + (size_t)gr * 512 + j0) = db;
    __syncthreads();
    float o[8] = {};
    const float* a_s = a_ls[wid];
    for (int k = 0; k < CATPI; ++k) {
        float a = a_s[k];
        short8 w = *(const short8*)(Wpibf + k * 512 + j0);
#pragma unroll
        for (int e = 0; e < 8; ++e) o[e] += a * b2f(w[e]);
    }
    float s2 = 0.f, q2 = 0.f;
#pragma unroll
    for (int e = 0; e < 8; ++e) {
        s2 += o[e];
        q2 += o[e] * o[e];
    }
    wred2(s2, q2);
    float m2 = s2 * (1.f / 512.f), iv2 = rsqrtf(q2 * (1.f / 512.f) - m2 * m2 + LNEPS);
    short8 xo;
#pragma unroll
    for (int e = 0; e < 8; ++e) xo[e] = f2b(siluf_((o[e] - m2) * iv2 * g_pi[j0 + e] + b_pi[j0 + e]));
    *(short8*)(xbf + (size_t)gr * 512 + j0) = xo;
}

// ---- block-wide reduction (k_init only) ----
template <int NV>
__device__ __forceinline__ void breduce(float* v, float* red, int nwaves) {
    __syncthreads();
#pragma unroll
    for (int off = 32; off > 0; off >>= 1)
#pragma unroll
        for (int q = 0; q < NV; ++q) v[q] += __shfl_down(v[q], off);
    int lane = threadIdx.x & 63, w = threadIdx.x >> 6;
    if (lane == 0)
        for (int q = 0; q < NV; ++q) red[w * NV + q] = v[q];
    __syncthreads();
    if ((int)threadIdx.x < NV) {
        float s = 0.f;
        for (int ww = 0; ww < nwaves; ++ww) s += red[ww * NV + threadIdx.x];
        red[nwaves * NV + threadIdx.x] = s;
    }
    __syncthreads();
#pragma unroll
    for (int q = 0; q < NV; ++q) v[q] = red[nwaves * NV + q];
}

__global__ __launch_bounds__(512) void k_init(const float* __restrict__ init_deter, const float* __restrict__ W_po,
                                              const float* __restrict__ g_po, const float* __restrict__ b_po,
                                              const float* __restrict__ W_ps, const float* __restrict__ b_ps,
                                              float* __restrict__ dinit, float* __restrict__ sinit) {
    __shared__ float d_s[512], h_s[512], red[40];
    int tid = threadIdx.x;
    float dv = tanhf(init_deter[tid]);
    d_s[tid] = dv;
    dinit[tid] = dv;
    __syncthreads();
    float acc = 0.f;
    for (int k = 0; k < 512; ++k) acc += d_s[k] * W_po[k * 512 + tid];
    float v[2] = {acc, acc * acc};
    breduce<2>(v, red, 8);
    float m = v[0] / 512.f, va = v[1] / 512.f - m * m, iv = rsqrtf(va + LNEPS);
    h_s[tid] = siluf_((acc - m) * iv * g_po[tid] + b_po[tid]);
    __syncthreads();
    if (tid < 32) {
        float s = b_ps[tid];
        for (int k = 0; k < 512; ++k) s += h_s[k] * W_ps[k * 64 + tid];
        sinit[tid] = s;
    }
}

__global__ __launch_bounds__(256) void k_transpose_bf(const float* __restrict__ src,
                                                      __hip_bfloat16* __restrict__ dst, int K, int N) {
    __shared__ float tle[32][33];
    int nTK = K >> 5;
    int k0 = (blockIdx.x % nTK) * 32;
    int n0 = (blockIdx.x / nTK) * 32;
    int tx = threadIdx.x & 31, ty = threadIdx.x >> 5;
#pragma unroll
    for (int i = 0; i < 4; ++i) tle[ty + i * 8][tx] = src[(size_t)(k0 + ty + i * 8) * N + n0 + tx];
    __syncthreads();
#pragma unroll
    for (int i = 0; i < 4; ++i)
        dst[(size_t)(n0 + ty + i * 8) * K + k0 + tx] = __float2bfloat16(tle[tx][ty + i * 8]);
}

__global__ __launch_bounds__(256) void k_cvt_bf(const float* __restrict__ src, __hip_bfloat16* __restrict__ dst,
                                                int n) {
    for (int i = blockIdx.x * 256 + threadIdx.x; i < n; i += gridDim.x * 256) dst[i] = __float2bfloat16(src[i]);
}

extern "C" void kernel_launch(void* const* d_in, const int* in_sizes, int n_in, void* d_out, int out_size, void* d_ws,
                              size_t ws_size, hipStream_t stream) {
    const float* obs = (const float*)d_in[0];
    const float* action = (const float*)d_in[1];
    const int* is_first = (const int*)d_in[2];
    const float* W_pi = (const float*)d_in[3];
    const float* g_pi = (const float*)d_in[4];
    const float* b_pi = (const float*)d_in[5];
    const float* W_gru = (const float*)d_in[6];
    const float* g_gru = (const float*)d_in[7];
    const float* b_gru = (const float*)d_in[8];
    const float* W_po = (const float*)d_in[9];
    const float* g_po = (const float*)d_in[10];
    const float* b_po = (const float*)d_in[11];
    const float* W_ps = (const float*)d_in[12];
    const float* b_ps = (const float*)d_in[13];
    const float* W_pn = (const float*)d_in[14];
    const float* g_pn = (const float*)d_in[15];
    const float* b_pn = (const float*)d_in[16];
    const float* W_pt = (const float*)d_in[17];
    const float* b_pt = (const float*)d_in[18];
    const float* init_deter = (const float*)d_in[19];
    float* out = (float*)d_out;

    char* p = (char*)d_ws;
    auto alloc = [&](size_t bytes) {
        char* r = p;
        p += (bytes + 255) & ~(size_t)255;
        return r;
    };
    float* gates = (float*)alloc((size_t)BB * G3N * 4);
    float* deter = (float*)alloc((size_t)BB * 512 * 4);
    float* hq_raw = (float*)alloc((size_t)BB * 512 * 4);
    float* dinit = (float*)alloc(512 * 4);
    float* sinit = (float*)alloc(64 * 4);
    __hip_bfloat16* xbf = (__hip_bfloat16*)alloc((size_t)BB * 512 * 2);
    __hip_bfloat16* dbf = (__hip_bfloat16*)alloc((size_t)BB * 512 * 2);
    __hip_bfloat16* obsbf = (__hip_bfloat16*)alloc((size_t)BB * TT * OBSN * 2);
    __hip_bfloat16* WgT = (__hip_bfloat16*)alloc((size_t)G3N * 1024 * 2);
    __hip_bfloat16* WpoT = (__hip_bfloat16*)alloc((size_t)512 * 512 * 2);
    __hip_bfloat16* WpnT = (__hip_bfloat16*)alloc((size_t)512 * 576 * 2);
    __hip_bfloat16* WpsT = (__hip_bfloat16*)alloc((size_t)64 * 512 * 2);
    __hip_bfloat16* WptT = (__hip_bfloat16*)alloc((size_t)64 * 512 * 2);
    __hip_bfloat16* Wpibf = (__hip_bfloat16*)alloc((size_t)CATPI * 512 * 2);

    k_transpose_bf<<<(1024 / 32) * (G3N / 32), 256, 0, stream>>>(W_gru, WgT, 1024, G3N);
    k_transpose_bf<<<(512 / 32) * (512 / 32), 256, 0, stream>>>(W_po, WpoT, 512, 512);
    k_transpose_bf<<<(576 / 32) * (512 / 32), 256, 0, stream>>>(W_pn, WpnT, 576, 512);
    k_transpose_bf<<<(512 / 32) * (64 / 32), 256, 0, stream>>>(W_ps, WpsT, 512, 64);
    k_transpose_bf<<<(512 / 32) * (64 / 32), 256, 0, stream>>>(W_pt, WptT, 512, 64);
    k_cvt_bf<<<80, 256, 0, stream>>>(W_pi, Wpibf, CATPI * 512);
    k_cvt_bf<<<2048, 256, 0, stream>>>(obs, obsbf, BB * TT * OBSN);
    k_init<<<1, 512, 0, stream>>>(init_deter, W_po, g_po, b_po, W_ps, b_ps, dinit, sinit);
    k_prior0<<<256, 256, 0, stream>>>(is_first, action, dinit, sinit, Wpibf, g_pi, b_pi, deter, dbf, xbf);

    for (int t = 0; t < TT; ++t) {
        k_gemm_gru<<<256, 256, 0, stream>>>(xbf, dbf, WgT, gates);
        k_update<<<128, 256, 0, stream>>>(t, gates, g_gru, b_gru, deter, dbf, out);
        k_gemm_hq<<<128, 256, 0, stream>>>(t, dbf, obsbf, WpnT, hq_raw);
        k_finish<<<256, 256, 0, stream>>>(t, hq_raw, g_pn, b_pn, WptT, b_pt, is_first, action, dinit, sinit, deter,
                                          dbf, Wpibf, g_pi, b_pi, xbf, out);
    }
    k_post_p<<<BB * TT / 16, 512, 0, stream>>>(out, WpoT, g_po, b_po, WpsT, b_ps, out);
}